// Round 1
// baseline (58228.796 us; speedup 1.0000x reference)
//
#include <hip/hip_runtime.h>

#define B_ 128
#define S_ 256
#define H_ 1024
#define V_ 512
#define T_ 128
#define G4 4096

// ---------- helpers ----------
__device__ __forceinline__ float bf2f(unsigned short x) {
    unsigned int u = ((unsigned int)x) << 16;
    return __builtin_bit_cast(float, u);
}
__device__ __forceinline__ unsigned short f2b(float f) {
    unsigned int u = __builtin_bit_cast(unsigned int, f);
    u = u + 0x7fffu + ((u >> 16) & 1u);
    return (unsigned short)(u >> 16);
}
__device__ __forceinline__ float sigm(float x) { return 1.f / (1.f + expf(-x)); }

// ---------- small precompute kernels ----------
__global__ void f32_to_bf16_x4(const float4* __restrict__ in, ushort4* __restrict__ out, int n4) {
    int i = blockIdx.x * 256 + threadIdx.x;
    if (i < n4) {
        float4 v = in[i];
        ushort4 o;
        o.x = f2b(v.x); o.y = f2b(v.y); o.z = f2b(v.z); o.w = f2b(v.w);
        out[i] = o;
    }
}

__global__ void build_toks(const int* __restrict__ target, int* __restrict__ toks) {
    int idx = blockIdx.x * 256 + threadIdx.x; // 0 .. T_*B_-1
    if (idx < T_ * B_) {
        int t = idx / B_, b = idx % B_;
        toks[idx] = (t == 0) ? 0 : target[b * T_ + t - 1];
    }
}

__global__ void build_bsum(const float* __restrict__ b_ih, const float* __restrict__ b_hh,
                           float* __restrict__ bsum) {
    int i = blockIdx.x * 256 + threadIdx.x;
    if (i < G4) bsum[i] = b_ih[i] + b_hh[i];
}

__global__ void transpose_outw(const float* __restrict__ out_w, float* __restrict__ owT) {
    int idx = blockIdx.x * 256 + threadIdx.x; // k*512+v
    if (idx < H_ * V_) {
        int v = idx & (V_ - 1);
        int k = idx >> 9;
        owT[idx] = out_w[(size_t)v * H_ + k];
    }
}

// ---------- generic f32 GEMM: C[M,N] = A[M,K] * Bw[N,K]^T (+bias +rowBias +acc) ----------
template<bool OUT_BF16, bool ACC, bool ROWBIAS>
__global__ __launch_bounds__(256) void gemm_tn(
    const float* __restrict__ A, int lda,
    const float* __restrict__ Bw, int ldb,
    float* __restrict__ C, unsigned short* __restrict__ Cb, int ldc,
    const float* __restrict__ bias,
    const float* __restrict__ rowBias, int ldrb, const int* __restrict__ rowIdx,
    int K)
{
    __shared__ float As[16][65];
    __shared__ float Bs[16][65];
    const int m0 = blockIdx.x * 64;
    const int n0 = blockIdx.y * 64;
    const int tid = threadIdx.x;
    const int tx = tid & 15, ty = tid >> 4;
    const int lr = tid >> 2;            // 0..63
    const int lc = (tid & 3) << 2;      // 0,4,8,12
    float acc[4][4] = {};
    const float* ap = A + (size_t)(m0 + lr) * lda + lc;
    const float* bp = Bw + (size_t)(n0 + lr) * ldb + lc;
    for (int k0 = 0; k0 < K; k0 += 16) {
        float4 av = *reinterpret_cast<const float4*>(ap + k0);
        float4 bv = *reinterpret_cast<const float4*>(bp + k0);
        As[lc + 0][lr] = av.x; As[lc + 1][lr] = av.y; As[lc + 2][lr] = av.z; As[lc + 3][lr] = av.w;
        Bs[lc + 0][lr] = bv.x; Bs[lc + 1][lr] = bv.y; Bs[lc + 2][lr] = bv.z; Bs[lc + 3][lr] = bv.w;
        __syncthreads();
        #pragma unroll
        for (int kk = 0; kk < 16; ++kk) {
            float a[4], b[4];
            #pragma unroll
            for (int i = 0; i < 4; ++i) a[i] = As[kk][ty * 4 + i];
            #pragma unroll
            for (int j = 0; j < 4; ++j) b[j] = Bs[kk][tx * 4 + j];
            #pragma unroll
            for (int i = 0; i < 4; ++i)
                #pragma unroll
                for (int j = 0; j < 4; ++j)
                    acc[i][j] += a[i] * b[j];
        }
        __syncthreads();
    }
    #pragma unroll
    for (int i = 0; i < 4; ++i) {
        int row = m0 + ty * 4 + i;
        const float* rb = nullptr;
        if (ROWBIAS) rb = rowBias + (size_t)rowIdx[row] * ldrb;
        #pragma unroll
        for (int j = 0; j < 4; ++j) {
            int col = n0 + tx * 4 + j;
            float v = acc[i][j];
            if (bias) v += bias[col];
            if (ROWBIAS) v += rb[col];
            size_t off = (size_t)row * ldc + col;
            if (ACC) v += C[off];
            if (OUT_BF16) Cb[off] = f2b(v); else C[off] = v;
        }
    }
}

// ---------- fused attention step: energies + softmax + attn-store + context ----------
__global__ __launch_bounds__(512) void attn_step(
    const unsigned short* __restrict__ kp,   // [B*S, H] bf16
    const float* __restrict__ q,             // [B, H]
    const float* __restrict__ Va,            // [H]
    const unsigned short* __restrict__ encb, // [B*S, H] bf16
    float* __restrict__ ctx,                 // [B, H]
    float* __restrict__ attnOut,             // base of attn output [B,T,S]
    int t)
{
    const int b = blockIdx.x;
    const int tid = threadIdx.x;
    const int lane = tid & 63;
    const int wv = tid >> 6; // 0..7
    __shared__ float qs[H_];
    __shared__ float vas[H_];
    __shared__ float es[S_];
    __shared__ float redm[8], reds[8];

    for (int i = tid; i < H_; i += 512) { qs[i] = q[b * H_ + i]; vas[i] = Va[i]; }
    __syncthreads();

    // energies: wave wv handles s = wv*32 .. wv*32+31
    for (int si = 0; si < 32; ++si) {
        int s = wv * 32 + si;
        const unsigned short* kr = kp + (size_t)(b * S_ + s) * H_;
        float acc = 0.f;
        for (int h4 = lane * 4; h4 < H_; h4 += 256) {
            ushort4 u = *reinterpret_cast<const ushort4*>(kr + h4);
            acc += vas[h4 + 0] * tanhf(qs[h4 + 0] + bf2f(u.x));
            acc += vas[h4 + 1] * tanhf(qs[h4 + 1] + bf2f(u.y));
            acc += vas[h4 + 2] * tanhf(qs[h4 + 2] + bf2f(u.z));
            acc += vas[h4 + 3] * tanhf(qs[h4 + 3] + bf2f(u.w));
        }
        #pragma unroll
        for (int off = 32; off; off >>= 1) acc += __shfl_down(acc, off);
        if (lane == 0) es[s] = acc;
    }
    __syncthreads();

    // softmax over S_=256 (threads 0..255 hold values; all participate in barriers)
    float x = (tid < S_) ? es[tid] : -3.4e38f;
    float mx = x;
    #pragma unroll
    for (int off = 32; off; off >>= 1) mx = fmaxf(mx, __shfl_xor(mx, off));
    if (lane == 0) redm[wv] = mx;
    __syncthreads();
    mx = redm[0];
    #pragma unroll
    for (int i = 1; i < 8; ++i) mx = fmaxf(mx, redm[i]);
    float ex = (tid < S_) ? expf(x - mx) : 0.f;
    float sm = ex;
    #pragma unroll
    for (int off = 32; off; off >>= 1) sm += __shfl_xor(sm, off);
    if (lane == 0) reds[wv] = sm;
    __syncthreads();
    sm = 0.f;
    #pragma unroll
    for (int i = 0; i < 8; ++i) sm += reds[i];
    float wnorm = ex / sm;
    if (tid < S_) {
        es[tid] = wnorm;
        attnOut[((size_t)(b * T_ + t)) * S_ + tid] = wnorm;
    }
    __syncthreads();

    // context: thread handles h = tid*2, tid*2+1
    const ushort2* erow = reinterpret_cast<const ushort2*>(encb) + (size_t)b * S_ * (H_ / 2) + tid;
    float acc0 = 0.f, acc1 = 0.f;
    #pragma unroll 4
    for (int s = 0; s < S_; ++s) {
        ushort2 u = erow[(size_t)s * (H_ / 2)];
        float w = es[s];
        acc0 += w * bf2f(u.x);
        acc1 += w * bf2f(u.y);
    }
    ctx[b * H_ + tid * 2 + 0] = acc0;
    ctx[b * H_ + tid * 2 + 1] = acc1;
}

// ---------- LSTM pointwise ----------
__global__ __launch_bounds__(256) void lstm_point(
    const float* __restrict__ gates, float* __restrict__ c, float* __restrict__ h,
    float* __restrict__ hidOut, int last)
{
    int idx = blockIdx.x * 256 + threadIdx.x; // 0 .. B*H-1
    int b = idx >> 10;
    int hh = idx & (H_ - 1);
    const float* g = gates + (size_t)b * G4;
    float iv = g[hh], fv = g[H_ + hh], gv = g[2 * H_ + hh], ov = g[3 * H_ + hh];
    float cn = sigm(fv) * c[idx] + sigm(iv) * tanhf(gv);
    float hn = sigm(ov) * tanhf(cn);
    c[idx] = cn;
    h[idx] = hn;
    if (last) hidOut[idx] = hn;
}

// ---------- logits + log-softmax ----------
__global__ __launch_bounds__(256) void logits_lsm(
    const float* __restrict__ h, const float* __restrict__ owT, // [H][V]
    const float* __restrict__ out_b, float* __restrict__ lp, int t)
{
    const int b = blockIdx.x;
    const int tid = threadIdx.x;
    __shared__ float hs[H_];
    __shared__ float redm[4], reds[4];
    for (int i = tid; i < H_; i += 256) hs[i] = h[b * H_ + i];
    __syncthreads();
    float a0 = out_b[tid], a1 = out_b[tid + 256];
    #pragma unroll 4
    for (int k = 0; k < H_; ++k) {
        float hv = hs[k];
        a0 += hv * owT[k * V_ + tid];
        a1 += hv * owT[k * V_ + tid + 256];
    }
    float mx = fmaxf(a0, a1);
    #pragma unroll
    for (int off = 32; off; off >>= 1) mx = fmaxf(mx, __shfl_xor(mx, off));
    if ((tid & 63) == 0) redm[tid >> 6] = mx;
    __syncthreads();
    mx = fmaxf(fmaxf(redm[0], redm[1]), fmaxf(redm[2], redm[3]));
    float e0 = expf(a0 - mx), e1 = expf(a1 - mx);
    float sm = e0 + e1;
    #pragma unroll
    for (int off = 32; off; off >>= 1) sm += __shfl_xor(sm, off);
    if ((tid & 63) == 0) reds[tid >> 6] = sm;
    __syncthreads();
    sm = reds[0] + reds[1] + reds[2] + reds[3];
    float lse = mx + logf(sm);
    size_t off = ((size_t)b * T_ + t) * V_;
    lp[off + tid] = a0 - lse;
    lp[off + tid + 256] = a1 - lse;
}

// ---------- launch ----------
extern "C" void kernel_launch(void* const* d_in, const int* in_sizes, int n_in,
                              void* d_out, int out_size, void* d_ws, size_t ws_size,
                              hipStream_t stream) {
    const float* enc   = (const float*)d_in[0];
    const float* h0    = (const float*)d_in[1];
    const float* c0    = (const float*)d_in[2];
    const int*   targ  = (const int*)d_in[3];
    const float* emb   = (const float*)d_in[5];
    const float* Wa_w  = (const float*)d_in[6];
    const float* Wa_b  = (const float*)d_in[7];
    const float* Ua_w  = (const float*)d_in[8];
    const float* Ua_b  = (const float*)d_in[9];
    const float* Va_w  = (const float*)d_in[10];
    const float* W_ih  = (const float*)d_in[12];
    const float* W_hh  = (const float*)d_in[13];
    const float* b_ih  = (const float*)d_in[14];
    const float* b_hh  = (const float*)d_in[15];
    const float* out_w = (const float*)d_in[16];
    const float* out_b = (const float*)d_in[17];

    float* out  = (float*)d_out;
    float* lp   = out;                          // [B,T,V]
    float* hid  = out + (size_t)B_ * T_ * V_;   // [B,H]
    float* attn = hid + (size_t)B_ * H_;        // [B,T,S]

    // workspace carve
    char* w = (char*)d_ws;
    auto alloc = [&](size_t bytes) {
        char* p = w;
        w += (bytes + 255) & ~(size_t)255;
        return p;
    };
    const size_t NKP = (size_t)B_ * S_ * H_;
    unsigned short* kp    = (unsigned short*)alloc(NKP * 2);
    unsigned short* encb  = (unsigned short*)alloc(NKP * 2);
    float* Pemb  = (float*)alloc((size_t)V_ * G4 * 4);
    float* owT   = (float*)alloc((size_t)H_ * V_ * 4);
    float* bsum  = (float*)alloc((size_t)G4 * 4);
    int*   toks  = (int*)alloc((size_t)T_ * B_ * 4);
    float* hbuf  = (float*)alloc((size_t)B_ * H_ * 4);
    float* cbuf  = (float*)alloc((size_t)B_ * H_ * 4);
    float* qbuf  = (float*)alloc((size_t)B_ * H_ * 4);
    float* ctx   = (float*)alloc((size_t)B_ * H_ * 4);
    float* gates = (float*)alloc((size_t)B_ * G4 * 4);
    if ((size_t)(w - (char*)d_ws) > ws_size) return; // ws too small: fail visibly

    // init state
    hipMemcpyAsync(hbuf, h0, (size_t)B_ * H_ * 4, hipMemcpyDeviceToDevice, stream);
    hipMemcpyAsync(cbuf, c0, (size_t)B_ * H_ * 4, hipMemcpyDeviceToDevice, stream);

    // precompute
    {
        int n4 = (int)(NKP / 4);
        f32_to_bf16_x4<<<(n4 + 255) / 256, 256, 0, stream>>>((const float4*)enc, (ushort4*)encb, n4);
        build_toks<<<(T_ * B_ + 255) / 256, 256, 0, stream>>>(targ, toks);
        build_bsum<<<(G4 + 255) / 256, 256, 0, stream>>>(b_ih, b_hh, bsum);
        transpose_outw<<<(H_ * V_ + 255) / 256, 256, 0, stream>>>(out_w, owT);
        // keys_proj (bf16 out): [B*S,H] x [H,H]^T
        dim3 g((B_ * S_) / 64, H_ / 64);
        gemm_tn<true, false, false><<<g, 256, 0, stream>>>(
            enc, H_, Ua_w, H_, nullptr, kp, H_, Ua_b, nullptr, 0, nullptr, H_);
        // P_emb: [V,H] x W_ih[:, :H]^T  (+ b_ih + b_hh)
        dim3 g2(V_ / 64, G4 / 64);
        gemm_tn<false, false, false><<<g2, 256, 0, stream>>>(
            emb, H_, W_ih, 2 * H_, Pemb, nullptr, G4, bsum, nullptr, 0, nullptr, H_);
    }

    // sequential decode
    for (int t = 0; t < T_; ++t) {
        // q = h @ Wa_w^T + Wa_b
        dim3 gq(B_ / 64, H_ / 64);
        gemm_tn<false, false, false><<<gq, 256, 0, stream>>>(
            hbuf, H_, Wa_w, H_, qbuf, nullptr, H_, Wa_b, nullptr, 0, nullptr, H_);
        // attention (energies + softmax + attn store + context)
        attn_step<<<B_, 512, 0, stream>>>(kp, qbuf, Va_w, encb, ctx, attn, t);
        // gates = ctx @ W_ih[:, H:]^T + P_emb[tok]   then += h @ W_hh^T
        dim3 gg(B_ / 64, G4 / 64);
        gemm_tn<false, false, true><<<gg, 256, 0, stream>>>(
            ctx, H_, W_ih + H_, 2 * H_, gates, nullptr, G4, nullptr,
            Pemb, G4, toks + t * B_, H_);
        gemm_tn<false, true, false><<<gg, 256, 0, stream>>>(
            hbuf, H_, W_hh, H_, gates, nullptr, G4, nullptr, nullptr, 0, nullptr, H_);
        // LSTM pointwise
        lstm_point<<<(B_ * H_) / 256, 256, 0, stream>>>(gates, cbuf, hbuf, hid, t == T_ - 1);
        // logits + log-softmax
        logits_lsm<<<B_, 256, 0, stream>>>(hbuf, owT, out_b, lp, t);
    }
}

// Round 2
// 16397.223 us; speedup vs baseline: 3.5511x; 3.5511x over previous
//
#include <hip/hip_runtime.h>

#define B_ 128
#define S_ 256
#define H_ 1024
#define V_ 512
#define T_ 128
#define G4 4096

typedef __attribute__((ext_vector_type(8))) short bf16x8;
typedef __attribute__((ext_vector_type(4))) float f32x4;

// ---------- helpers ----------
__device__ __forceinline__ float bf2f(unsigned short x) {
    unsigned int u = ((unsigned int)x) << 16;
    return __builtin_bit_cast(float, u);
}
__device__ __forceinline__ unsigned short f2b(float f) {
    unsigned int u = __builtin_bit_cast(unsigned int, f);
    u = u + 0x7fffu + ((u >> 16) & 1u);
    return (unsigned short)(u >> 16);
}
__device__ __forceinline__ float ftanh(float x) {
    float e = __expf(2.f * x);
    return 1.f - 2.f * __builtin_amdgcn_rcpf(e + 1.f);
}
__device__ __forceinline__ float fsigm(float x) {
    return __builtin_amdgcn_rcpf(1.f + __expf(-x));
}
__device__ __forceinline__ void gll16(const void* g, void* l) {
    __builtin_amdgcn_global_load_lds(
        (const __attribute__((address_space(1))) unsigned int*)g,
        (__attribute__((address_space(3))) unsigned int*)l, 16, 0, 0);
}

// ---------- small precompute kernels ----------
__global__ void f32_to_bf16_x4(const float4* __restrict__ in, ushort4* __restrict__ out, int n4) {
    int i = blockIdx.x * 256 + threadIdx.x;
    if (i < n4) {
        float4 v = in[i];
        ushort4 o;
        o.x = f2b(v.x); o.y = f2b(v.y); o.z = f2b(v.z); o.w = f2b(v.w);
        out[i] = o;
    }
}

__global__ void build_toks(const int* __restrict__ target, int* __restrict__ toks) {
    int idx = blockIdx.x * 256 + threadIdx.x;
    if (idx < T_ * B_) {
        int t = idx / B_, b = idx % B_;
        toks[idx] = (t == 0) ? 0 : target[b * T_ + t - 1];
    }
}

__global__ void build_bsum(const float* __restrict__ b_ih, const float* __restrict__ b_hh,
                           float* __restrict__ bsum) {
    int i = blockIdx.x * 256 + threadIdx.x;
    if (i < G4) bsum[i] = b_ih[i] + b_hh[i];
}

// ---------- bf16 MFMA GEMM: C[M,N] = A[M,K](bf16) * Bw[N,ldb](bf16)^T ----------
// 64x64 tile, BK=64, 4 waves (each a 32x32 quadrant of 2x2 16x16x32 MFMA frags).
// LDS layout: [64 rows][8 chunks of 16B], chunk slot XOR-swizzled with (row&7) so
// ds_read_b128 spreads over banks; global_load_lds writes linearly, so the global
// source chunk is pre-swizzled with the same XOR (both-sides-or-neither rule).
// MODE 0: C[row*ldc+col] = v + bias[col]           (f32 out)
// MODE 1: Cb[row*ldc+col] = bf16(v + bias[col])    (bf16 out; keys_proj)
// MODE 2: col<H_: Cq[row*H_+col] = v + bias[col];  else C[row*G4+col-H_] = v + Pemb[tok[row]][col-H_]
// MODE 3: C[row*ldc+col] += v                      (gates accumulate)
template<int MODE>
__global__ __launch_bounds__(256) void gemm_mf(
    const unsigned short* __restrict__ A,
    const unsigned short* __restrict__ Bw,
    int K, int ldb, int ldc,
    float* __restrict__ C, unsigned short* __restrict__ Cb,
    const float* __restrict__ bias,
    const float* __restrict__ Pemb,
    const int* __restrict__ toks,
    float* __restrict__ Cq)
{
    __shared__ unsigned short As[64 * 64];
    __shared__ unsigned short Bs[64 * 64];
    const int tid = threadIdx.x;
    const int lane = tid & 63;
    const int wv = tid >> 6;
    const int m0 = blockIdx.x * 64;
    const int n0 = blockIdx.y * 64;

    // staging: 512 16B-chunks per matrix, 2 per thread
    const int ci0 = tid, ci1 = 256 + tid;
    const int row0 = ci0 >> 3, row1 = ci1 >> 3;
    const int cs0 = (ci0 & 7) ^ (row0 & 7);
    const int cs1 = (ci1 & 7) ^ (row1 & 7);
    const unsigned short* ga0 = A + (size_t)(m0 + row0) * K + cs0 * 8;
    const unsigned short* ga1 = A + (size_t)(m0 + row1) * K + cs1 * 8;
    const unsigned short* gb0 = Bw + (size_t)(n0 + row0) * ldb + cs0 * 8;
    const unsigned short* gb1 = Bw + (size_t)(n0 + row1) * ldb + cs1 * 8;
    unsigned short* lA0 = As + (wv * 64) * 8;
    unsigned short* lA1 = As + (256 + wv * 64) * 8;
    unsigned short* lB0 = Bs + (wv * 64) * 8;
    unsigned short* lB1 = Bs + (256 + wv * 64) * 8;

    f32x4 acc[2][2] = {};
    const int r0 = (wv >> 1) * 32;   // quadrant rows
    const int cq0 = (wv & 1) * 32;   // quadrant cols
    const int fr = lane & 15;
    const int kg = lane >> 4;

    for (int k0 = 0; k0 < K; k0 += 64) {
        gll16(ga0 + k0, lA0);
        gll16(ga1 + k0, lA1);
        gll16(gb0 + k0, lB0);
        gll16(gb1 + k0, lB1);
        __syncthreads();
        bf16x8 af[2][2], bf[2][2];
        #pragma unroll
        for (int f = 0; f < 2; ++f)
            #pragma unroll
            for (int kh = 0; kh < 2; ++kh) {
                int ra = r0 + f * 16 + fr;
                af[f][kh] = *(const bf16x8*)&As[ra * 64 + ((((kh * 4 + kg) ^ (ra & 7))) << 3)];
                int rb = cq0 + f * 16 + fr;
                bf[f][kh] = *(const bf16x8*)&Bs[rb * 64 + ((((kh * 4 + kg) ^ (rb & 7))) << 3)];
            }
        #pragma unroll
        for (int f = 0; f < 2; ++f)
            #pragma unroll
            for (int g = 0; g < 2; ++g)
                #pragma unroll
                for (int kh = 0; kh < 2; ++kh)
                    acc[f][g] = __builtin_amdgcn_mfma_f32_16x16x32_bf16(
                        af[f][kh], bf[g][kh], acc[f][g], 0, 0, 0);
        __syncthreads();
    }

    const int erow = (lane >> 4) * 4;
    const int ecol = lane & 15;
    #pragma unroll
    for (int f = 0; f < 2; ++f) {
        #pragma unroll
        for (int g = 0; g < 2; ++g) {
            #pragma unroll
            for (int r = 0; r < 4; ++r) {
                int row = m0 + r0 + f * 16 + erow + r;
                int col = n0 + cq0 + g * 16 + ecol;
                float v = acc[f][g][r];
                if (MODE == 0) {
                    C[(size_t)row * ldc + col] = v + bias[col];
                } else if (MODE == 1) {
                    Cb[(size_t)row * ldc + col] = f2b(v + bias[col]);
                } else if (MODE == 2) {
                    if (col < H_) Cq[(size_t)row * H_ + col] = v + bias[col];
                    else {
                        int cg = col - H_;
                        C[(size_t)row * G4 + cg] = v + Pemb[(size_t)toks[row] * G4 + cg];
                    }
                } else {
                    C[(size_t)row * ldc + col] += v;
                }
            }
        }
    }
}

// ---------- fused attention step ----------
__global__ __launch_bounds__(512) void attn_step(
    const unsigned short* __restrict__ kp,   // [B*S, H] bf16
    const float* __restrict__ q,             // [B, H]
    const float* __restrict__ Va,            // [H]
    const unsigned short* __restrict__ encb, // [B*S, H] bf16
    unsigned short* __restrict__ ctxb,       // [B, H] bf16
    float* __restrict__ attnOut,             // [B,T,S]
    int t)
{
    const int b = blockIdx.x;
    const int tid = threadIdx.x;
    const int lane = tid & 63;
    const int wv = tid >> 6; // 0..7
    __shared__ float qs[H_];
    __shared__ float vas[H_];
    __shared__ float es[S_];
    __shared__ float redm[8], reds[8];

    for (int i = tid; i < H_; i += 512) { qs[i] = q[b * H_ + i]; vas[i] = Va[i]; }
    __syncthreads();

    for (int si = 0; si < 32; ++si) {
        int s = wv * 32 + si;
        const unsigned short* kr = kp + (size_t)(b * S_ + s) * H_;
        float acc = 0.f;
        for (int h4 = lane * 4; h4 < H_; h4 += 256) {
            ushort4 u = *reinterpret_cast<const ushort4*>(kr + h4);
            acc += vas[h4 + 0] * ftanh(qs[h4 + 0] + bf2f(u.x));
            acc += vas[h4 + 1] * ftanh(qs[h4 + 1] + bf2f(u.y));
            acc += vas[h4 + 2] * ftanh(qs[h4 + 2] + bf2f(u.z));
            acc += vas[h4 + 3] * ftanh(qs[h4 + 3] + bf2f(u.w));
        }
        #pragma unroll
        for (int off = 32; off; off >>= 1) acc += __shfl_down(acc, off);
        if (lane == 0) es[s] = acc;
    }
    __syncthreads();

    float x = (tid < S_) ? es[tid] : -3.4e38f;
    float mx = x;
    #pragma unroll
    for (int off = 32; off; off >>= 1) mx = fmaxf(mx, __shfl_xor(mx, off));
    if (lane == 0) redm[wv] = mx;
    __syncthreads();
    mx = redm[0];
    #pragma unroll
    for (int i = 1; i < 8; ++i) mx = fmaxf(mx, redm[i]);
    float ex = (tid < S_) ? __expf(x - mx) : 0.f;
    float sm = ex;
    #pragma unroll
    for (int off = 32; off; off >>= 1) sm += __shfl_xor(sm, off);
    if (lane == 0) reds[wv] = sm;
    __syncthreads();
    sm = 0.f;
    #pragma unroll
    for (int i = 0; i < 8; ++i) sm += reds[i];
    float wnorm = ex * __builtin_amdgcn_rcpf(sm);
    if (tid < S_) {
        es[tid] = wnorm;
        attnOut[((size_t)(b * T_ + t)) * S_ + tid] = wnorm;
    }
    __syncthreads();

    // context: thread handles h = tid*2, tid*2+1
    const ushort2* erow2 = reinterpret_cast<const ushort2*>(encb) + (size_t)b * S_ * (H_ / 2) + tid;
    float acc0 = 0.f, acc1 = 0.f;
    #pragma unroll 4
    for (int s = 0; s < S_; ++s) {
        ushort2 u = erow2[(size_t)s * (H_ / 2)];
        float w = es[s];
        acc0 += w * bf2f(u.x);
        acc1 += w * bf2f(u.y);
    }
    ushort2 o; o.x = f2b(acc0); o.y = f2b(acc1);
    *reinterpret_cast<ushort2*>(&ctxb[(size_t)b * H_ + tid * 2]) = o;
}

// ---------- LSTM pointwise ----------
__global__ __launch_bounds__(256) void lstm_point(
    const float* __restrict__ gates, float* __restrict__ c, float* __restrict__ h,
    unsigned short* __restrict__ hb, float* __restrict__ hidOut, int last)
{
    int idx = blockIdx.x * 256 + threadIdx.x;
    int b = idx >> 10;
    int hh = idx & (H_ - 1);
    const float* g = gates + (size_t)b * G4;
    float iv = g[hh], fv = g[H_ + hh], gv = g[2 * H_ + hh], ov = g[3 * H_ + hh];
    float cn = fsigm(fv) * c[idx] + fsigm(iv) * ftanh(gv);
    float hn = fsigm(ov) * ftanh(cn);
    c[idx] = cn;
    h[idx] = hn;
    hb[idx] = f2b(hn);
    if (last) hidOut[idx] = hn;
}

// ---------- log-softmax over V=512 ----------
__global__ __launch_bounds__(256) void lsm_kernel(
    const float* __restrict__ lg, float* __restrict__ lp, int t)
{
    int b = blockIdx.x, tid = threadIdx.x;
    int lane = tid & 63, wv = tid >> 6;
    __shared__ float red[4];
    float a0 = lg[(size_t)b * V_ + tid];
    float a1 = lg[(size_t)b * V_ + 256 + tid];
    float mx = fmaxf(a0, a1);
    #pragma unroll
    for (int off = 32; off; off >>= 1) mx = fmaxf(mx, __shfl_xor(mx, off));
    if (lane == 0) red[wv] = mx;
    __syncthreads();
    mx = fmaxf(fmaxf(red[0], red[1]), fmaxf(red[2], red[3]));
    float sm = __expf(a0 - mx) + __expf(a1 - mx);
    #pragma unroll
    for (int off = 32; off; off >>= 1) sm += __shfl_xor(sm, off);
    __syncthreads();
    if (lane == 0) red[wv] = sm;
    __syncthreads();
    sm = red[0] + red[1] + red[2] + red[3];
    float lse = mx + __logf(sm);
    size_t off = ((size_t)b * T_ + t) * V_;
    lp[off + tid] = a0 - lse;
    lp[off + tid + 256] = a1 - lse;
}

// ---------- launch ----------
extern "C" void kernel_launch(void* const* d_in, const int* in_sizes, int n_in,
                              void* d_out, int out_size, void* d_ws, size_t ws_size,
                              hipStream_t stream) {
    const float* enc   = (const float*)d_in[0];
    const float* h0    = (const float*)d_in[1];
    const float* c0    = (const float*)d_in[2];
    const int*   targ  = (const int*)d_in[3];
    const float* emb   = (const float*)d_in[5];
    const float* Wa_w  = (const float*)d_in[6];
    const float* Wa_b  = (const float*)d_in[7];
    const float* Ua_w  = (const float*)d_in[8];
    const float* Ua_b  = (const float*)d_in[9];
    const float* Va_w  = (const float*)d_in[10];
    const float* W_ih  = (const float*)d_in[12];
    const float* W_hh  = (const float*)d_in[13];
    const float* b_ih  = (const float*)d_in[14];
    const float* b_hh  = (const float*)d_in[15];
    const float* out_w = (const float*)d_in[16];
    const float* out_b = (const float*)d_in[17];

    float* out  = (float*)d_out;
    float* lp   = out;                          // [B,T,V]
    float* hid  = out + (size_t)B_ * T_ * V_;   // [1,B,H]
    float* attn = hid + (size_t)B_ * H_;        // [B,T,S]

    char* w = (char*)d_ws;
    auto alloc = [&](size_t bytes) {
        char* p = w;
        w += (bytes + 255) & ~(size_t)255;
        return p;
    };
    const size_t NKP = (size_t)B_ * S_ * H_;
    unsigned short* kp     = (unsigned short*)alloc(NKP * 2);
    unsigned short* encb   = (unsigned short*)alloc(NKP * 2);
    unsigned short* Wih_b  = (unsigned short*)alloc((size_t)G4 * 2048 * 2);
    unsigned short* Wcat_b = (unsigned short*)alloc((size_t)5120 * H_ * 2);
    unsigned short* Uaw_b  = (unsigned short*)alloc((size_t)H_ * H_ * 2);
    unsigned short* emb_b  = (unsigned short*)alloc((size_t)V_ * H_ * 2);
    unsigned short* owb    = (unsigned short*)alloc((size_t)V_ * H_ * 2);
    unsigned short* hb     = (unsigned short*)alloc((size_t)B_ * H_ * 2);
    unsigned short* ctxb   = (unsigned short*)alloc((size_t)B_ * H_ * 2);
    float* Pemb  = (float*)alloc((size_t)V_ * G4 * 4);
    float* bsum  = (float*)alloc((size_t)G4 * 4);
    int*   toks  = (int*)alloc((size_t)T_ * B_ * 4);
    float* hbuf  = (float*)alloc((size_t)B_ * H_ * 4);
    float* cbuf  = (float*)alloc((size_t)B_ * H_ * 4);
    float* qbuf  = (float*)alloc((size_t)B_ * H_ * 4);
    float* gates = (float*)alloc((size_t)B_ * G4 * 4);
    float* lgbuf = (float*)alloc((size_t)B_ * V_ * 4);
    if ((size_t)(w - (char*)d_ws) > ws_size) return;

    auto cvt = [&](const float* src, unsigned short* dst, size_t n) {
        int n4 = (int)(n / 4);
        f32_to_bf16_x4<<<(n4 + 255) / 256, 256, 0, stream>>>((const float4*)src, (ushort4*)dst, n4);
    };

    // precompute
    cvt(enc, encb, NKP);
    cvt(W_ih, Wih_b, (size_t)G4 * 2048);
    cvt(Wa_w, Wcat_b, (size_t)H_ * H_);
    cvt(W_hh, Wcat_b + (size_t)H_ * H_, (size_t)G4 * H_);
    cvt(Ua_w, Uaw_b, (size_t)H_ * H_);
    cvt(emb, emb_b, (size_t)V_ * H_);
    cvt(out_w, owb, (size_t)V_ * H_);
    cvt(h0, hb, (size_t)B_ * H_);
    build_toks<<<(T_ * B_ + 255) / 256, 256, 0, stream>>>(targ, toks);
    build_bsum<<<(G4 + 255) / 256, 256, 0, stream>>>(b_ih, b_hh, bsum);
    hipMemcpyAsync(cbuf, c0, (size_t)B_ * H_ * 4, hipMemcpyDeviceToDevice, stream);

    // keys_proj: kp[B*S,H] = encb @ Ua_w^T + Ua_b  (bf16 out)
    gemm_mf<1><<<dim3((B_ * S_) / 64, H_ / 64), 256, 0, stream>>>(
        encb, Uaw_b, H_, H_, H_, nullptr, kp, Ua_b, nullptr, nullptr, nullptr);
    // Pemb[V,4H] = emb_b @ W_ih[:, :H]^T + (b_ih+b_hh)
    gemm_mf<0><<<dim3(V_ / 64, G4 / 64), 256, 0, stream>>>(
        emb_b, Wih_b, H_, 2 * H_, G4, Pemb, nullptr, bsum, nullptr, nullptr, nullptr);

    // sequential decode
    for (int t = 0; t < T_; ++t) {
        // [q | gates_h] = hb @ [Wa_w; W_hh]^T, split epilogue (+Wa_b / +Pemb[tok])
        gemm_mf<2><<<dim3(B_ / 64, 5120 / 64), 256, 0, stream>>>(
            hb, Wcat_b, H_, H_, 0, gates, nullptr, Wa_b, Pemb, toks + t * B_, qbuf);
        attn_step<<<B_, 512, 0, stream>>>(kp, qbuf, Va_w, encb, ctxb, attn, t);
        // gates += ctxb @ W_ih[:, H:2H]^T
        gemm_mf<3><<<dim3(B_ / 64, G4 / 64), 256, 0, stream>>>(
            ctxb, Wih_b + H_, H_, 2 * H_, G4, gates, nullptr, nullptr, nullptr, nullptr, nullptr);
        lstm_point<<<(B_ * H_) / 256, 256, 0, stream>>>(gates, cbuf, hbuf, hb, hid, t == T_ - 1);
        // logits = hb(h_t) @ out_w^T + out_b
        gemm_mf<0><<<dim3(B_ / 64, V_ / 64), 256, 0, stream>>>(
            hb, owb, H_, H_, V_, lgbuf, nullptr, out_b, nullptr, nullptr, nullptr);
        lsm_kernel<<<B_, 256, 0, stream>>>(lgbuf, lp, t);
    }
}

// Round 3
// 9068.786 us; speedup vs baseline: 6.4208x; 1.8081x over previous
//
#include <hip/hip_runtime.h>

#define B_ 128
#define S_ 256
#define H_ 1024
#define V_ 512
#define T_ 128
#define G4 4096

typedef __attribute__((ext_vector_type(8))) short bf16x8;
typedef __attribute__((ext_vector_type(4))) float f32x4;

// ---------- helpers ----------
__device__ __forceinline__ float bf2f(unsigned short x) {
    unsigned int u = ((unsigned int)x) << 16;
    return __builtin_bit_cast(float, u);
}
__device__ __forceinline__ unsigned short f2b(float f) {
    unsigned int u = __builtin_bit_cast(unsigned int, f);
    u = u + 0x7fffu + ((u >> 16) & 1u);
    return (unsigned short)(u >> 16);
}
__device__ __forceinline__ float ftanh(float x) {
    float e = __expf(2.f * x);
    return 1.f - 2.f * __builtin_amdgcn_rcpf(e + 1.f);
}
__device__ __forceinline__ float fsigm(float x) {
    return __builtin_amdgcn_rcpf(1.f + __expf(-x));
}
__device__ __forceinline__ void gll16(const void* g, void* l) {
    __builtin_amdgcn_global_load_lds(
        (const __attribute__((address_space(1))) unsigned int*)g,
        (__attribute__((address_space(3))) unsigned int*)l, 16, 0, 0);
}

// ---------- small precompute kernels ----------
__global__ void f32_to_bf16_x4(const float4* __restrict__ in, ushort4* __restrict__ out, int n4) {
    int i = blockIdx.x * 256 + threadIdx.x;
    if (i < n4) {
        float4 v = in[i];
        ushort4 o;
        o.x = f2b(v.x); o.y = f2b(v.y); o.z = f2b(v.z); o.w = f2b(v.w);
        out[i] = o;
    }
}

// dst[r][0..1023] (bf16) = src[perm(r)][coff..coff+1023]; perm: gate-interleave or identity
__global__ void cvt_gather(const float* __restrict__ src, int src_ld, int coff,
                           unsigned short* __restrict__ dst, int perm) {
    int i = blockIdx.x * 256 + threadIdx.x;   // one per 4 cols; grid = nrows blocks
    int r = i >> 8;
    int c = (i & 255) * 4;
    int sr = perm ? (((r & 3) << 10) + (r >> 2)) : r;
    float4 v = *reinterpret_cast<const float4*>(src + (size_t)sr * src_ld + coff + c);
    ushort4 o;
    o.x = f2b(v.x); o.y = f2b(v.y); o.z = f2b(v.z); o.w = f2b(v.w);
    *reinterpret_cast<ushort4*>(dst + (size_t)r * 1024 + c) = o;
}

__global__ void build_toks(const int* __restrict__ target, int* __restrict__ toks) {
    int idx = blockIdx.x * 256 + threadIdx.x;
    if (idx < T_ * B_) {
        int t = idx / B_, b = idx % B_;
        toks[idx] = (t == 0) ? 0 : target[b * T_ + t - 1];
    }
}

// permuted bias sum: bsumP[j] = b_ih[p(j)] + b_hh[p(j)]
__global__ void build_bsum(const float* __restrict__ b_ih, const float* __restrict__ b_hh,
                           float* __restrict__ bsum) {
    int j = blockIdx.x * 256 + threadIdx.x;
    if (j < G4) {
        int pj = ((j & 3) << 10) + (j >> 2);
        bsum[j] = b_ih[pj] + b_hh[pj];
    }
}

// ---------- bf16 MFMA GEMM with 2-phase LDS prefetch ----------
// C[M,N] = A[M,K](bf16) * Bw[N,ldb](bf16)^T, 64x64 tile, BK=64, 4 waves.
// MODE 0: C[row*ldc+col] = v + bias[col]                       (f32 out)
// MODE 1: Cb[row*ldc+col] = bf16(v + bias[col])                (keys_proj)
// MODE 2: col<1024   -> Cq[row*H+col] = v + Wa_b[col]          (q)
//         col<5120   -> C[row*G4+cg] = v + Pemb[tok[row]][cg]  (gates partial, permuted)
//         else       -> Lg[row*V+cl] = v + bias2[cl]           (logits of prev step)
// MODE 4: gates-acc + fused LSTM pointwise epilogue:
//         reads C (partial gates), Cq=c-state (rw), writes Cb=h bf16, Lg=hid f32 (if flag)
template<int MODE>
__global__ __launch_bounds__(256) void gemm_mf(
    const unsigned short* __restrict__ A,
    const unsigned short* __restrict__ Bw,
    int K, int ldb, int ldc,
    float* __restrict__ C, unsigned short* __restrict__ Cb,
    const float* __restrict__ bias,
    const float* __restrict__ Pemb,
    const int* __restrict__ toks,
    float* __restrict__ Cq,
    float* __restrict__ Lg,
    const float* __restrict__ bias2,
    int flag)
{
    __shared__ unsigned short As[2 * 4096];
    __shared__ unsigned short Bs[2 * 4096];
    const int tid = threadIdx.x;
    const int lane = tid & 63;
    const int wv = tid >> 6;
    const int m0 = blockIdx.x * 64;
    const int n0 = blockIdx.y * 64;

    const int ci0 = tid, ci1 = 256 + tid;
    const int row0 = ci0 >> 3, row1 = ci1 >> 3;
    const int cs0 = (ci0 & 7) ^ (row0 & 7);
    const int cs1 = (ci1 & 7) ^ (row1 & 7);
    const unsigned short* ga0 = A + (size_t)(m0 + row0) * K + cs0 * 8;
    const unsigned short* ga1 = A + (size_t)(m0 + row1) * K + cs1 * 8;
    const unsigned short* gb0 = Bw + (size_t)(n0 + row0) * ldb + cs0 * 8;
    const unsigned short* gb1 = Bw + (size_t)(n0 + row1) * ldb + cs1 * 8;

    f32x4 acc[2][2] = {};
    const int r0 = (wv >> 1) * 32;
    const int cq0 = (wv & 1) * 32;
    const int fr = lane & 15;
    const int kg = lane >> 4;

    auto stage = [&](int k0, int p) {
        unsigned short* a0 = As + p * 4096 + wv * 512;
        unsigned short* a1 = As + p * 4096 + 2048 + wv * 512;
        unsigned short* b0 = Bs + p * 4096 + wv * 512;
        unsigned short* b1 = Bs + p * 4096 + 2048 + wv * 512;
        gll16(ga0 + k0, a0);
        gll16(ga1 + k0, a1);
        gll16(gb0 + k0, b0);
        gll16(gb1 + k0, b1);
    };

    stage(0, 0);
    __syncthreads();
    int p = 0;
    for (int k0 = 0; k0 < K; k0 += 64) {
        if (k0 + 64 < K) stage(k0 + 64, p ^ 1);
        const unsigned short* Ab = As + p * 4096;
        const unsigned short* Bb = Bs + p * 4096;
        bf16x8 af[2][2], bfr[2][2];
        #pragma unroll
        for (int f = 0; f < 2; ++f)
            #pragma unroll
            for (int kh = 0; kh < 2; ++kh) {
                int ra = r0 + f * 16 + fr;
                af[f][kh] = *(const bf16x8*)&Ab[ra * 64 + (((kh * 4 + kg) ^ (ra & 7)) << 3)];
                int rb = cq0 + f * 16 + fr;
                bfr[f][kh] = *(const bf16x8*)&Bb[rb * 64 + (((kh * 4 + kg) ^ (rb & 7)) << 3)];
            }
        #pragma unroll
        for (int f = 0; f < 2; ++f)
            #pragma unroll
            for (int g = 0; g < 2; ++g)
                #pragma unroll
                for (int kh = 0; kh < 2; ++kh)
                    acc[f][g] = __builtin_amdgcn_mfma_f32_16x16x32_bf16(
                        af[f][kh], bfr[g][kh], acc[f][g], 0, 0, 0);
        __syncthreads();
        p ^= 1;
    }

    const int erow = (lane >> 4) * 4;
    const int ecol = lane & 15;

    if constexpr (MODE == 4) {
        __shared__ float Lt[64 * 64];
        #pragma unroll
        for (int f = 0; f < 2; ++f)
            #pragma unroll
            for (int g = 0; g < 2; ++g)
                #pragma unroll
                for (int r = 0; r < 4; ++r)
                    Lt[(r0 + f * 16 + erow + r) * 64 + cq0 + g * 16 + ecol] = acc[f][g][r];
        __syncthreads();
        #pragma unroll
        for (int i = 0; i < 4; ++i) {
            int pi = tid + 256 * i;
            int r = pi >> 4, u = pi & 15;
            int b = m0 + r;
            int hh = (n0 >> 2) + u;
            f32x4 gv = *reinterpret_cast<const f32x4*>(&Lt[r * 64 + u * 4]);
            const float* gp = C + (size_t)b * G4 + n0 + u * 4;
            float iv = gv[0] + gp[0];
            float fv = gv[1] + gp[1];
            float gg = gv[2] + gp[2];
            float ov = gv[3] + gp[3];
            int ci = b * H_ + hh;
            float cn = fsigm(fv) * Cq[ci] + fsigm(iv) * ftanh(gg);
            float hn = fsigm(ov) * ftanh(cn);
            Cq[ci] = cn;
            Cb[ci] = f2b(hn);
            if (flag) Lg[ci] = hn;
        }
    } else {
        #pragma unroll
        for (int f = 0; f < 2; ++f) {
            #pragma unroll
            for (int g = 0; g < 2; ++g) {
                #pragma unroll
                for (int r = 0; r < 4; ++r) {
                    int row = m0 + r0 + f * 16 + erow + r;
                    int col = n0 + cq0 + g * 16 + ecol;
                    float v = acc[f][g][r];
                    if (MODE == 0) {
                        C[(size_t)row * ldc + col] = v + bias[col];
                    } else if (MODE == 1) {
                        Cb[(size_t)row * ldc + col] = f2b(v + bias[col]);
                    } else if (MODE == 2) {
                        if (col < H_) {
                            Cq[(size_t)row * H_ + col] = v + bias[col];
                        } else if (col < 5120) {
                            int cg = col - H_;
                            C[(size_t)row * G4 + cg] = v + Pemb[(size_t)toks[row] * G4 + cg];
                        } else {
                            int cl = col - 5120;
                            Lg[(size_t)row * V_ + cl] = v + bias2[cl];
                        }
                    }
                }
            }
        }
    }
}

// ---------- fused: lsm(t-1) + attention step ----------
__global__ __launch_bounds__(1024) void attn_step(
    const unsigned short* __restrict__ kp,   // [B*S, H] bf16
    const float* __restrict__ q,             // [B, H]
    const float* __restrict__ Va,            // [H]
    const unsigned short* __restrict__ encb, // [B*S, H] bf16
    unsigned short* __restrict__ ctxb,       // [B, H] bf16
    float* __restrict__ attnOut,             // [B,T,S]
    const float* __restrict__ lg,            // [B, V] logits of step t-1
    float* __restrict__ lp,                  // [B,T,V] log-probs out
    int t)
{
    const int b = blockIdx.x;
    const int tid = threadIdx.x;
    const int lane = tid & 63;
    const int wv = tid >> 6; // 0..15
    __shared__ float qs[H_];
    __shared__ float vas[H_];
    __shared__ float es[S_];
    __shared__ float redm[16], reds[16];
    __shared__ float cpart[H_];

    qs[tid] = q[(size_t)b * H_ + tid];
    vas[tid] = Va[tid];

    // ---- log-softmax for step t-1 (free ride on this launch) ----
    const bool doLsm = (t > 0);
    float lsA = -3.4e38f;
    if (doLsm && tid < V_) lsA = lg[(size_t)b * V_ + tid];
    float m1 = lsA;
    #pragma unroll
    for (int off = 32; off; off >>= 1) m1 = fmaxf(m1, __shfl_xor(m1, off));
    if (lane == 0) redm[wv] = m1;
    __syncthreads();                       // also publishes qs/vas
    float gm = redm[0];
    #pragma unroll
    for (int i = 1; i < 16; ++i) gm = fmaxf(gm, redm[i]);
    float lex = (doLsm && tid < V_) ? __expf(lsA - gm) : 0.f;
    float s1 = lex;
    #pragma unroll
    for (int off = 32; off; off >>= 1) s1 += __shfl_xor(s1, off);
    if (lane == 0) reds[wv] = s1;
    __syncthreads();
    float gs = 0.f;
    #pragma unroll
    for (int i = 0; i < 16; ++i) gs += reds[i];
    if (doLsm && tid < V_)
        lp[((size_t)b * T_ + (t - 1)) * V_ + tid] = lsA - gm - __logf(gs);

    // ---- energies: wave wv handles s = wv*16 .. wv*16+15 ----
    for (int si = 0; si < 16; ++si) {
        int s = wv * 16 + si;
        const unsigned short* kr = kp + (size_t)(b * S_ + s) * H_;
        float acc = 0.f;
        #pragma unroll
        for (int it = 0; it < 4; ++it) {
            int h4 = lane * 4 + it * 256;
            ushort4 u = *reinterpret_cast<const ushort4*>(kr + h4);
            acc += vas[h4 + 0] * ftanh(qs[h4 + 0] + bf2f(u.x));
            acc += vas[h4 + 1] * ftanh(qs[h4 + 1] + bf2f(u.y));
            acc += vas[h4 + 2] * ftanh(qs[h4 + 2] + bf2f(u.z));
            acc += vas[h4 + 3] * ftanh(qs[h4 + 3] + bf2f(u.w));
        }
        #pragma unroll
        for (int off = 32; off; off >>= 1) acc += __shfl_down(acc, off);
        if (lane == 0) es[s] = acc;
    }
    __syncthreads();

    // ---- softmax over S=256 ----
    float x = (tid < S_) ? es[tid] : -3.4e38f;
    float mx = x;
    #pragma unroll
    for (int off = 32; off; off >>= 1) mx = fmaxf(mx, __shfl_xor(mx, off));
    if (lane == 0) redm[wv] = mx;
    __syncthreads();
    mx = redm[0];
    #pragma unroll
    for (int i = 1; i < 16; ++i) mx = fmaxf(mx, redm[i]);
    float ex = (tid < S_) ? __expf(x - mx) : 0.f;
    float sm = ex;
    #pragma unroll
    for (int off = 32; off; off >>= 1) sm += __shfl_xor(sm, off);
    if (lane == 0) reds[wv] = sm;
    __syncthreads();
    sm = 0.f;
    #pragma unroll
    for (int i = 0; i < 16; ++i) sm += reds[i];
    float wnorm = ex * __builtin_amdgcn_rcpf(sm);
    if (tid < S_) {
        es[tid] = wnorm;
        attnOut[((size_t)(b * T_ + t)) * S_ + tid] = wnorm;
    }
    __syncthreads();

    // ---- context: s-range split across two halves of the block ----
    const int shalf = tid >> 9;   // 0/1
    const int hp = tid & 511;     // h-pair
    const ushort2* er = reinterpret_cast<const ushort2*>(encb)
                        + ((size_t)b * S_ + shalf * 128) * (H_ / 2) + hp;
    float a0 = 0.f, a1 = 0.f;
    #pragma unroll 4
    for (int s = 0; s < 128; ++s) {
        ushort2 u = er[(size_t)s * (H_ / 2)];
        float w = es[shalf * 128 + s];
        a0 += w * bf2f(u.x);
        a1 += w * bf2f(u.y);
    }
    if (shalf) { cpart[hp * 2] = a0; cpart[hp * 2 + 1] = a1; }
    __syncthreads();
    if (!shalf) {
        a0 += cpart[hp * 2];
        a1 += cpart[hp * 2 + 1];
        ushort2 o; o.x = f2b(a0); o.y = f2b(a1);
        *reinterpret_cast<ushort2*>(&ctxb[(size_t)b * H_ + hp * 2]) = o;
    }
}

// ---------- standalone log-softmax (final step only) ----------
__global__ __launch_bounds__(256) void lsm_kernel(
    const float* __restrict__ lg, float* __restrict__ lp, int t)
{
    int b = blockIdx.x, tid = threadIdx.x;
    int lane = tid & 63, wv = tid >> 6;
    __shared__ float red[4];
    float a0 = lg[(size_t)b * V_ + tid];
    float a1 = lg[(size_t)b * V_ + 256 + tid];
    float mx = fmaxf(a0, a1);
    #pragma unroll
    for (int off = 32; off; off >>= 1) mx = fmaxf(mx, __shfl_xor(mx, off));
    if (lane == 0) red[wv] = mx;
    __syncthreads();
    mx = fmaxf(fmaxf(red[0], red[1]), fmaxf(red[2], red[3]));
    float sm = __expf(a0 - mx) + __expf(a1 - mx);
    #pragma unroll
    for (int off = 32; off; off >>= 1) sm += __shfl_xor(sm, off);
    __syncthreads();
    if (lane == 0) red[wv] = sm;
    __syncthreads();
    sm = red[0] + red[1] + red[2] + red[3];
    float lse = mx + __logf(sm);
    size_t off = ((size_t)b * T_ + t) * V_;
    lp[off + tid] = a0 - lse;
    lp[off + tid + 256] = a1 - lse;
}

// ---------- launch ----------
extern "C" void kernel_launch(void* const* d_in, const int* in_sizes, int n_in,
                              void* d_out, int out_size, void* d_ws, size_t ws_size,
                              hipStream_t stream) {
    const float* enc   = (const float*)d_in[0];
    const float* h0    = (const float*)d_in[1];
    const float* c0    = (const float*)d_in[2];
    const int*   targ  = (const int*)d_in[3];
    const float* emb   = (const float*)d_in[5];
    const float* Wa_w  = (const float*)d_in[6];
    const float* Wa_b  = (const float*)d_in[7];
    const float* Ua_w  = (const float*)d_in[8];
    const float* Ua_b  = (const float*)d_in[9];
    const float* Va_w  = (const float*)d_in[10];
    const float* W_ih  = (const float*)d_in[12];
    const float* W_hh  = (const float*)d_in[13];
    const float* b_ih  = (const float*)d_in[14];
    const float* b_hh  = (const float*)d_in[15];
    const float* out_w = (const float*)d_in[16];
    const float* out_b = (const float*)d_in[17];

    float* out  = (float*)d_out;
    float* lp   = out;                          // [B,T,V]
    float* hid  = out + (size_t)B_ * T_ * V_;   // [1,B,H]
    float* attn = hid + (size_t)B_ * H_;        // [B,T,S]

    char* w = (char*)d_ws;
    auto alloc = [&](size_t bytes) {
        char* p = w;
        w += (bytes + 255) & ~(size_t)255;
        return p;
    };
    const size_t NKP = (size_t)B_ * S_ * H_;
    unsigned short* kp     = (unsigned short*)alloc(NKP * 2);
    unsigned short* encb   = (unsigned short*)alloc(NKP * 2);
    unsigned short* Wcat_b = (unsigned short*)alloc((size_t)5632 * H_ * 2); // [Wa; W_hh(perm); out_w]
    unsigned short* Wih1_b = (unsigned short*)alloc((size_t)G4 * H_ * 2);   // W_ih[:, :H] perm
    unsigned short* Wih2_b = (unsigned short*)alloc((size_t)G4 * H_ * 2);   // W_ih[:, H:] perm
    unsigned short* Uaw_b  = (unsigned short*)alloc((size_t)H_ * H_ * 2);
    unsigned short* emb_b  = (unsigned short*)alloc((size_t)V_ * H_ * 2);
    unsigned short* hb     = (unsigned short*)alloc((size_t)B_ * H_ * 2);
    unsigned short* ctxb   = (unsigned short*)alloc((size_t)B_ * H_ * 2);
    float* Pemb  = (float*)alloc((size_t)V_ * G4 * 4);  // permuted gate layout
    float* bsumP = (float*)alloc((size_t)G4 * 4);
    int*   toks  = (int*)alloc((size_t)T_ * B_ * 4);
    float* cbuf  = (float*)alloc((size_t)B_ * H_ * 4);
    float* qbuf  = (float*)alloc((size_t)B_ * H_ * 4);
    float* gates = (float*)alloc((size_t)B_ * G4 * 4);
    float* lgbuf = (float*)alloc((size_t)B_ * V_ * 4);
    if ((size_t)(w - (char*)d_ws) > ws_size) return;

    auto cvt = [&](const float* src, unsigned short* dst, size_t n) {
        int n4 = (int)(n / 4);
        f32_to_bf16_x4<<<(n4 + 255) / 256, 256, 0, stream>>>((const float4*)src, (ushort4*)dst, n4);
    };

    // precompute: conversions + permuted weight layouts
    cvt(enc, encb, NKP);
    cvt(Ua_w, Uaw_b, (size_t)H_ * H_);
    cvt(emb, emb_b, (size_t)V_ * H_);
    cvt(h0, hb, (size_t)B_ * H_);
    cvt_gather<<<1024, 256, 0, stream>>>(Wa_w, H_, 0, Wcat_b, 0);
    cvt_gather<<<4096, 256, 0, stream>>>(W_hh, H_, 0, Wcat_b + (size_t)1024 * H_, 1);
    cvt_gather<<<512, 256, 0, stream>>>(out_w, H_, 0, Wcat_b + (size_t)5120 * H_, 0);
    cvt_gather<<<4096, 256, 0, stream>>>(W_ih, 2 * H_, 0, Wih1_b, 1);
    cvt_gather<<<4096, 256, 0, stream>>>(W_ih, 2 * H_, H_, Wih2_b, 1);
    build_toks<<<(T_ * B_ + 255) / 256, 256, 0, stream>>>(targ, toks);
    build_bsum<<<(G4 + 255) / 256, 256, 0, stream>>>(b_ih, b_hh, bsumP);
    hipMemcpyAsync(cbuf, c0, (size_t)B_ * H_ * 4, hipMemcpyDeviceToDevice, stream);

    // keys_proj: kp = encb @ Ua_w^T + Ua_b (bf16 out)
    gemm_mf<1><<<dim3((B_ * S_) / 64, H_ / 64), 256, 0, stream>>>(
        encb, Uaw_b, H_, H_, H_, nullptr, kp, Ua_b,
        nullptr, nullptr, nullptr, nullptr, nullptr, 0);
    // Pemb (permuted): emb @ W_ih[:, :H](perm)^T + bsumP
    gemm_mf<0><<<dim3(V_ / 64, G4 / 64), 256, 0, stream>>>(
        emb_b, Wih1_b, H_, H_, G4, Pemb, nullptr, bsumP,
        nullptr, nullptr, nullptr, nullptr, nullptr, 0);

    // sequential decode: 3 launches per step
    for (int t = 0; t < T_; ++t) {
        // h_{t-1} @ [Wa; W_hh(perm); out_w]^T -> q | gates-partial(+Pemb) | logits(t-1)
        gemm_mf<2><<<dim3(B_ / 64, 5632 / 64), 256, 0, stream>>>(
            hb, Wcat_b, H_, H_, 0, gates, nullptr, Wa_b,
            Pemb, toks + t * B_, qbuf, lgbuf, out_b, 0);
        // lsm(t-1) + attention
        attn_step<<<B_, 1024, 0, stream>>>(kp, qbuf, Va_w, encb, ctxb, attn, lgbuf, lp, t);
        // gates += ctx @ W_ih[:, H:](perm)^T, fused LSTM pointwise
        gemm_mf<4><<<dim3(B_ / 64, G4 / 64), 256, 0, stream>>>(
            ctxb, Wih2_b, H_, H_, 0, gates, hb, nullptr,
            nullptr, nullptr, cbuf, hid, nullptr, t == T_ - 1);
    }
    // logits + lsm for final step
    gemm_mf<0><<<dim3(B_ / 64, V_ / 64), 256, 0, stream>>>(
        hb, Wcat_b + (size_t)5120 * H_, H_, H_, V_, lgbuf, nullptr, out_b,
        nullptr, nullptr, nullptr, nullptr, nullptr, 0);
    lsm_kernel<<<B_, 256, 0, stream>>>(lgbuf, lp, T_ - 1);
}

// Round 4
// 7953.516 us; speedup vs baseline: 7.3211x; 1.1402x over previous
//
#include <hip/hip_runtime.h>

#define B_ 128
#define S_ 256
#define H_ 1024
#define V_ 512
#define T_ 128
#define G4 4096

typedef __attribute__((ext_vector_type(8))) short bf16x8;
typedef __attribute__((ext_vector_type(4))) float f32x4;

// ---------- helpers ----------
__device__ __forceinline__ float bf2f(unsigned short x) {
    unsigned int u = ((unsigned int)x) << 16;
    return __builtin_bit_cast(float, u);
}
__device__ __forceinline__ unsigned short f2b(float f) {
    unsigned int u = __builtin_bit_cast(unsigned int, f);
    u = u + 0x7fffu + ((u >> 16) & 1u);
    return (unsigned short)(u >> 16);
}
__device__ __forceinline__ float ftanh(float x) {
    float e = __expf(2.f * x);
    return 1.f - 2.f * __builtin_amdgcn_rcpf(e + 1.f);
}
__device__ __forceinline__ float fsigm(float x) {
    return __builtin_amdgcn_rcpf(1.f + __expf(-x));
}
__device__ __forceinline__ void gll16(const void* g, void* l) {
    __builtin_amdgcn_global_load_lds(
        (const __attribute__((address_space(1))) unsigned int*)g,
        (__attribute__((address_space(3))) unsigned int*)l, 16, 0, 0);
}

// ---------- small precompute kernels ----------
__global__ void f32_to_bf16_x4(const float4* __restrict__ in, ushort4* __restrict__ out, int n4) {
    int i = blockIdx.x * 256 + threadIdx.x;
    if (i < n4) {
        float4 v = in[i];
        ushort4 o;
        o.x = f2b(v.x); o.y = f2b(v.y); o.z = f2b(v.z); o.w = f2b(v.w);
        out[i] = o;
    }
}

// dst[r][0..1023] (bf16) = src[perm(r)][coff..coff+1023]; perm: gate-interleave or identity
__global__ void cvt_gather(const float* __restrict__ src, int src_ld, int coff,
                           unsigned short* __restrict__ dst, int perm) {
    int i = blockIdx.x * 256 + threadIdx.x;
    int r = i >> 8;
    int c = (i & 255) * 4;
    int sr = perm ? (((r & 3) << 10) + (r >> 2)) : r;
    float4 v = *reinterpret_cast<const float4*>(src + (size_t)sr * src_ld + coff + c);
    ushort4 o;
    o.x = f2b(v.x); o.y = f2b(v.y); o.z = f2b(v.z); o.w = f2b(v.w);
    *reinterpret_cast<ushort4*>(dst + (size_t)r * 1024 + c) = o;
}

__global__ void build_toks(const int* __restrict__ target, int* __restrict__ toks) {
    int idx = blockIdx.x * 256 + threadIdx.x;
    if (idx < T_ * B_) {
        int t = idx / B_, b = idx % B_;
        toks[idx] = (t == 0) ? 0 : target[b * T_ + t - 1];
    }
}

__global__ void build_bsum(const float* __restrict__ b_ih, const float* __restrict__ b_hh,
                           float* __restrict__ bsum) {
    int j = blockIdx.x * 256 + threadIdx.x;
    if (j < G4) {
        int pj = ((j & 3) << 10) + (j >> 2);
        bsum[j] = b_ih[pj] + b_hh[pj];
    }
}

// ---------- bf16 MFMA GEMM, BK=128, 2-phase prefetch ----------
// C[M,N] = A[M,K](bf16) * Bw[N,ldb](bf16)^T, 64x64 tile, 4 waves.
// MODE 0: C = v + bias[col]                      MODE 1: Cb = bf16(v + bias[col])
// MODE 2: col<1024 -> Cq=q; col<5120 -> gates(+Pemb[tok]); else logits(t-1)+bias2
// MODE 4: gates-acc + fused LSTM pointwise epilogue
template<int MODE>
__global__ __launch_bounds__(256) void gemm_mf(
    const unsigned short* __restrict__ A,
    const unsigned short* __restrict__ Bw,
    int K, int ldb, int ldc,
    float* __restrict__ C, unsigned short* __restrict__ Cb,
    const float* __restrict__ bias,
    const float* __restrict__ Pemb,
    const int* __restrict__ toks,
    float* __restrict__ Cq,
    float* __restrict__ Lg,
    const float* __restrict__ bias2,
    int flag)
{
    __shared__ unsigned short As[2 * 8192];   // 64 rows x 128 cols, double-buffered
    __shared__ unsigned short Bs[2 * 8192];
    const int tid = threadIdx.x;
    const int lane = tid & 63;
    const int wv = tid >> 6;
    const int m0 = blockIdx.x * 64;
    const int n0 = blockIdx.y * 64;

    // staging: 1024 16B-chunks per matrix, 4 per thread; slot XOR-swizzled by row
    const unsigned short* ga[4];
    const unsigned short* gb[4];
    #pragma unroll
    for (int j = 0; j < 4; ++j) {
        int ci = tid + 256 * j;
        int row = ci >> 4;
        int src = (ci & 15) ^ (row & 7);
        ga[j] = A + (size_t)(m0 + row) * K + src * 8;
        gb[j] = Bw + (size_t)(n0 + row) * ldb + src * 8;
    }

    f32x4 acc[2][2] = {};
    const int r0 = (wv >> 1) * 32;
    const int cq0 = (wv & 1) * 32;
    const int fr = lane & 15;
    const int kg = lane >> 4;

    auto stage = [&](int k0, int p) {
        #pragma unroll
        for (int j = 0; j < 4; ++j) {
            gll16(ga[j] + k0, As + p * 8192 + j * 2048 + wv * 512);
            gll16(gb[j] + k0, Bs + p * 8192 + j * 2048 + wv * 512);
        }
    };

    stage(0, 0);
    __syncthreads();
    int p = 0;
    for (int k0 = 0; k0 < K; k0 += 128) {
        if (k0 + 128 < K) stage(k0 + 128, p ^ 1);
        const unsigned short* Ab = As + p * 8192;
        const unsigned short* Bb = Bs + p * 8192;
        bf16x8 af[2][4], bfr[2][4];
        #pragma unroll
        for (int f = 0; f < 2; ++f)
            #pragma unroll
            for (int kh = 0; kh < 4; ++kh) {
                int ra = r0 + f * 16 + fr;
                af[f][kh] = *(const bf16x8*)&Ab[ra * 128 + (((kh * 4 + kg) ^ (ra & 7)) << 3)];
                int rb = cq0 + f * 16 + fr;
                bfr[f][kh] = *(const bf16x8*)&Bb[rb * 128 + (((kh * 4 + kg) ^ (rb & 7)) << 3)];
            }
        #pragma unroll
        for (int f = 0; f < 2; ++f)
            #pragma unroll
            for (int g = 0; g < 2; ++g)
                #pragma unroll
                for (int kh = 0; kh < 4; ++kh)
                    acc[f][g] = __builtin_amdgcn_mfma_f32_16x16x32_bf16(
                        af[f][kh], bfr[g][kh], acc[f][g], 0, 0, 0);
        __syncthreads();
        p ^= 1;
    }

    const int erow = (lane >> 4) * 4;
    const int ecol = lane & 15;

    if constexpr (MODE == 4) {
        __shared__ float Lt[64 * 64];
        #pragma unroll
        for (int f = 0; f < 2; ++f)
            #pragma unroll
            for (int g = 0; g < 2; ++g)
                #pragma unroll
                for (int r = 0; r < 4; ++r)
                    Lt[(r0 + f * 16 + erow + r) * 64 + cq0 + g * 16 + ecol] = acc[f][g][r];
        __syncthreads();
        #pragma unroll
        for (int i = 0; i < 4; ++i) {
            int pi = tid + 256 * i;
            int r = pi >> 4, u = pi & 15;
            int b = m0 + r;
            int hh = (n0 >> 2) + u;
            f32x4 gv = *reinterpret_cast<const f32x4*>(&Lt[r * 64 + u * 4]);
            const float* gp = C + (size_t)b * G4 + n0 + u * 4;
            float iv = gv[0] + gp[0];
            float fv = gv[1] + gp[1];
            float gg = gv[2] + gp[2];
            float ov = gv[3] + gp[3];
            int ci = b * H_ + hh;
            float cn = fsigm(fv) * Cq[ci] + fsigm(iv) * ftanh(gg);
            float hn = fsigm(ov) * ftanh(cn);
            Cq[ci] = cn;
            Cb[ci] = f2b(hn);
            if (flag) Lg[ci] = hn;
        }
    } else {
        #pragma unroll
        for (int f = 0; f < 2; ++f) {
            #pragma unroll
            for (int g = 0; g < 2; ++g) {
                #pragma unroll
                for (int r = 0; r < 4; ++r) {
                    int row = m0 + r0 + f * 16 + erow + r;
                    int col = n0 + cq0 + g * 16 + ecol;
                    float v = acc[f][g][r];
                    if (MODE == 0) {
                        C[(size_t)row * ldc + col] = v + bias[col];
                    } else if (MODE == 1) {
                        Cb[(size_t)row * ldc + col] = f2b(v + bias[col]);
                    } else if (MODE == 2) {
                        if (col < H_) {
                            Cq[(size_t)row * H_ + col] = v + bias[col];
                        } else if (col < 5120) {
                            int cg = col - H_;
                            C[(size_t)row * G4 + cg] = v + Pemb[(size_t)toks[row] * G4 + cg];
                        } else {
                            int cl = col - 5120;
                            Lg[(size_t)row * V_ + cl] = v + bias2[cl];
                        }
                    }
                }
            }
        }
    }
}

// ---------- attention energies (+ lsm of t-1), grid (B, 4) x 256 ----------
__global__ __launch_bounds__(256) void attn_e(
    const unsigned short* __restrict__ kp,   // [B*S, H] bf16
    const float* __restrict__ q,             // [B, H]
    const float* __restrict__ Va,            // [H]
    float* __restrict__ es_g,                // [B, S]
    const float* __restrict__ lg,            // [B, V] logits t-1
    float* __restrict__ lp,                  // [B,T,V]
    int t)
{
    const int b = blockIdx.x;
    const int sh = blockIdx.y;  // s-quarter
    const int tid = threadIdx.x;
    const int lane = tid & 63;
    const int wv = tid >> 6;    // 0..3
    __shared__ float qs[H_];
    __shared__ float vas[H_];
    __shared__ float redm[4], reds[4];

    for (int i = tid; i < H_; i += 256) {
        qs[i] = q[(size_t)b * H_ + i];
        vas[i] = Va[i];
    }

    // ---- log-softmax(t-1), done by sh==0 blocks; barriers unconditional ----
    const bool doL = (t > 0) && (sh == 0);
    float a0 = doL ? lg[(size_t)b * V_ + tid] : -3.4e38f;
    float a1 = doL ? lg[(size_t)b * V_ + 256 + tid] : -3.4e38f;
    float mx = fmaxf(a0, a1);
    #pragma unroll
    for (int off = 32; off; off >>= 1) mx = fmaxf(mx, __shfl_xor(mx, off));
    if (lane == 0) redm[wv] = mx;
    __syncthreads();                         // also publishes qs/vas
    mx = fmaxf(fmaxf(redm[0], redm[1]), fmaxf(redm[2], redm[3]));
    float sm = doL ? (__expf(a0 - mx) + __expf(a1 - mx)) : 0.f;
    #pragma unroll
    for (int off = 32; off; off >>= 1) sm += __shfl_xor(sm, off);
    if (lane == 0) reds[wv] = sm;
    __syncthreads();
    if (doL) {
        sm = reds[0] + reds[1] + reds[2] + reds[3];
        float lse = mx + __logf(sm);
        size_t off = ((size_t)b * T_ + (t - 1)) * V_;
        lp[off + tid] = a0 - lse;
        lp[off + tid + 256] = a1 - lse;
    }

    // ---- energies: wave wv handles s = sh*64 + wv*16 + 0..15 ----
    for (int si = 0; si < 16; ++si) {
        int s = sh * 64 + wv * 16 + si;
        const unsigned short* kr = kp + (size_t)(b * S_ + s) * H_;
        float acc = 0.f;
        #pragma unroll
        for (int it = 0; it < 4; ++it) {
            int h4 = lane * 4 + it * 256;
            ushort4 u = *reinterpret_cast<const ushort4*>(kr + h4);
            acc += vas[h4 + 0] * ftanh(qs[h4 + 0] + bf2f(u.x));
            acc += vas[h4 + 1] * ftanh(qs[h4 + 1] + bf2f(u.y));
            acc += vas[h4 + 2] * ftanh(qs[h4 + 2] + bf2f(u.z));
            acc += vas[h4 + 3] * ftanh(qs[h4 + 3] + bf2f(u.w));
        }
        #pragma unroll
        for (int off = 32; off; off >>= 1) acc += __shfl_down(acc, off);
        if (lane == 0) es_g[(size_t)b * S_ + s] = acc;
    }
}

// ---------- attention softmax + context slice, grid (B, 4) x 256 ----------
__global__ __launch_bounds__(256) void attn_c(
    const float* __restrict__ es_g,          // [B, S]
    const unsigned short* __restrict__ encb, // [B*S, H] bf16
    unsigned short* __restrict__ ctxb,       // [B, H] bf16
    float* __restrict__ attnOut,             // [B,T,S]
    int t)
{
    const int b = blockIdx.x;
    const int hh = blockIdx.y;  // h-quarter (256 cols)
    const int tid = threadIdx.x;
    const int lane = tid & 63;
    const int wv = tid >> 6;
    __shared__ float ws[S_];
    __shared__ float redm[4], reds[4];
    __shared__ float cpart[S_];

    // softmax over S=256 (redundant per block — cheap)
    float x = es_g[(size_t)b * S_ + tid];
    float mx = x;
    #pragma unroll
    for (int off = 32; off; off >>= 1) mx = fmaxf(mx, __shfl_xor(mx, off));
    if (lane == 0) redm[wv] = mx;
    __syncthreads();
    mx = fmaxf(fmaxf(redm[0], redm[1]), fmaxf(redm[2], redm[3]));
    float ex = __expf(x - mx);
    float sm = ex;
    #pragma unroll
    for (int off = 32; off; off >>= 1) sm += __shfl_xor(sm, off);
    if (lane == 0) reds[wv] = sm;
    __syncthreads();
    sm = reds[0] + reds[1] + reds[2] + reds[3];
    float w = ex * __builtin_amdgcn_rcpf(sm);
    ws[tid] = w;
    if (hh == 0) attnOut[((size_t)(b * T_ + t)) * S_ + tid] = w;
    __syncthreads();

    // context: thread (sH, cp): cols h = hh*256 + cp*2 (+1), s-range sH*128
    const int sH = tid >> 7;
    const int cp = tid & 127;
    const ushort2* er = reinterpret_cast<const ushort2*>(encb)
                        + ((size_t)b * S_ + sH * 128) * (H_ / 2) + hh * 128 + cp;
    float a0 = 0.f, a1 = 0.f;
    #pragma unroll 4
    for (int s = 0; s < 128; ++s) {
        ushort2 u = er[(size_t)s * (H_ / 2)];
        float wgt = ws[sH * 128 + s];
        a0 += wgt * bf2f(u.x);
        a1 += wgt * bf2f(u.y);
    }
    if (sH) { cpart[cp * 2] = a0; cpart[cp * 2 + 1] = a1; }
    __syncthreads();
    if (!sH) {
        a0 += cpart[cp * 2];
        a1 += cpart[cp * 2 + 1];
        ushort2 o; o.x = f2b(a0); o.y = f2b(a1);
        *reinterpret_cast<ushort2*>(&ctxb[(size_t)b * H_ + hh * 256 + cp * 2]) = o;
    }
}

// ---------- standalone log-softmax (final step only) ----------
__global__ __launch_bounds__(256) void lsm_kernel(
    const float* __restrict__ lg, float* __restrict__ lp, int t)
{
    int b = blockIdx.x, tid = threadIdx.x;
    int lane = tid & 63, wv = tid >> 6;
    __shared__ float red[4];
    float a0 = lg[(size_t)b * V_ + tid];
    float a1 = lg[(size_t)b * V_ + 256 + tid];
    float mx = fmaxf(a0, a1);
    #pragma unroll
    for (int off = 32; off; off >>= 1) mx = fmaxf(mx, __shfl_xor(mx, off));
    if (lane == 0) red[wv] = mx;
    __syncthreads();
    mx = fmaxf(fmaxf(red[0], red[1]), fmaxf(red[2], red[3]));
    float sm = __expf(a0 - mx) + __expf(a1 - mx);
    #pragma unroll
    for (int off = 32; off; off >>= 1) sm += __shfl_xor(sm, off);
    __syncthreads();
    if (lane == 0) red[wv] = sm;
    __syncthreads();
    sm = red[0] + red[1] + red[2] + red[3];
    float lse = mx + __logf(sm);
    size_t off = ((size_t)b * T_ + t) * V_;
    lp[off + tid] = a0 - lse;
    lp[off + tid + 256] = a1 - lse;
}

// ---------- launch ----------
extern "C" void kernel_launch(void* const* d_in, const int* in_sizes, int n_in,
                              void* d_out, int out_size, void* d_ws, size_t ws_size,
                              hipStream_t stream) {
    const float* enc   = (const float*)d_in[0];
    const float* h0    = (const float*)d_in[1];
    const float* c0    = (const float*)d_in[2];
    const int*   targ  = (const int*)d_in[3];
    const float* emb   = (const float*)d_in[5];
    const float* Wa_w  = (const float*)d_in[6];
    const float* Wa_b  = (const float*)d_in[7];
    const float* Ua_w  = (const float*)d_in[8];
    const float* Ua_b  = (const float*)d_in[9];
    const float* Va_w  = (const float*)d_in[10];
    const float* W_ih  = (const float*)d_in[12];
    const float* W_hh  = (const float*)d_in[13];
    const float* b_ih  = (const float*)d_in[14];
    const float* b_hh  = (const float*)d_in[15];
    const float* out_w = (const float*)d_in[16];
    const float* out_b = (const float*)d_in[17];

    float* out  = (float*)d_out;
    float* lp   = out;                          // [B,T,V]
    float* hid  = out + (size_t)B_ * T_ * V_;   // [1,B,H]
    float* attn = hid + (size_t)B_ * H_;        // [B,T,S]

    char* w = (char*)d_ws;
    auto alloc = [&](size_t bytes) {
        char* p = w;
        w += (bytes + 255) & ~(size_t)255;
        return p;
    };
    const size_t NKP = (size_t)B_ * S_ * H_;
    unsigned short* kp     = (unsigned short*)alloc(NKP * 2);
    unsigned short* encb   = (unsigned short*)alloc(NKP * 2);
    unsigned short* Wcat_b = (unsigned short*)alloc((size_t)5632 * H_ * 2); // [Wa; W_hh(perm); out_w]
    unsigned short* Wih1_b = (unsigned short*)alloc((size_t)G4 * H_ * 2);   // W_ih[:, :H] perm
    unsigned short* Wih2_b = (unsigned short*)alloc((size_t)G4 * H_ * 2);   // W_ih[:, H:] perm
    unsigned short* Uaw_b  = (unsigned short*)alloc((size_t)H_ * H_ * 2);
    unsigned short* emb_b  = (unsigned short*)alloc((size_t)V_ * H_ * 2);
    unsigned short* hb     = (unsigned short*)alloc((size_t)B_ * H_ * 2);
    unsigned short* ctxb   = (unsigned short*)alloc((size_t)B_ * H_ * 2);
    float* Pemb  = (float*)alloc((size_t)V_ * G4 * 4);
    float* bsumP = (float*)alloc((size_t)G4 * 4);
    int*   toks  = (int*)alloc((size_t)T_ * B_ * 4);
    float* cbuf  = (float*)alloc((size_t)B_ * H_ * 4);
    float* qbuf  = (float*)alloc((size_t)B_ * H_ * 4);
    float* gates = (float*)alloc((size_t)B_ * G4 * 4);
    float* lgbuf = (float*)alloc((size_t)B_ * V_ * 4);
    float* es_g  = (float*)alloc((size_t)B_ * S_ * 4);
    if ((size_t)(w - (char*)d_ws) > ws_size) return;

    auto cvt = [&](const float* src, unsigned short* dst, size_t n) {
        int n4 = (int)(n / 4);
        f32_to_bf16_x4<<<(n4 + 255) / 256, 256, 0, stream>>>((const float4*)src, (ushort4*)dst, n4);
    };

    // precompute
    cvt(enc, encb, NKP);
    cvt(Ua_w, Uaw_b, (size_t)H_ * H_);
    cvt(emb, emb_b, (size_t)V_ * H_);
    cvt(h0, hb, (size_t)B_ * H_);
    cvt_gather<<<1024, 256, 0, stream>>>(Wa_w, H_, 0, Wcat_b, 0);
    cvt_gather<<<4096, 256, 0, stream>>>(W_hh, H_, 0, Wcat_b + (size_t)1024 * H_, 1);
    cvt_gather<<<512, 256, 0, stream>>>(out_w, H_, 0, Wcat_b + (size_t)5120 * H_, 0);
    cvt_gather<<<4096, 256, 0, stream>>>(W_ih, 2 * H_, 0, Wih1_b, 1);
    cvt_gather<<<4096, 256, 0, stream>>>(W_ih, 2 * H_, H_, Wih2_b, 1);
    build_toks<<<(T_ * B_ + 255) / 256, 256, 0, stream>>>(targ, toks);
    build_bsum<<<(G4 + 255) / 256, 256, 0, stream>>>(b_ih, b_hh, bsumP);
    hipMemcpyAsync(cbuf, c0, (size_t)B_ * H_ * 4, hipMemcpyDeviceToDevice, stream);

    // keys_proj: kp = encb @ Ua_w^T + Ua_b (bf16 out)
    gemm_mf<1><<<dim3((B_ * S_) / 64, H_ / 64), 256, 0, stream>>>(
        encb, Uaw_b, H_, H_, H_, nullptr, kp, Ua_b,
        nullptr, nullptr, nullptr, nullptr, nullptr, 0);
    // Pemb (permuted): emb @ W_ih[:, :H](perm)^T + bsumP
    gemm_mf<0><<<dim3(V_ / 64, G4 / 64), 256, 0, stream>>>(
        emb_b, Wih1_b, H_, H_, G4, Pemb, nullptr, bsumP,
        nullptr, nullptr, nullptr, nullptr, nullptr, 0);

    // sequential decode: 4 launches per step
    for (int t = 0; t < T_; ++t) {
        gemm_mf<2><<<dim3(B_ / 64, 5632 / 64), 256, 0, stream>>>(
            hb, Wcat_b, H_, H_, 0, gates, nullptr, Wa_b,
            Pemb, toks + t * B_, qbuf, lgbuf, out_b, 0);
        attn_e<<<dim3(B_, 4), 256, 0, stream>>>(kp, qbuf, Va_w, es_g, lgbuf, lp, t);
        attn_c<<<dim3(B_, 4), 256, 0, stream>>>(es_g, encb, ctxb, attn, t);
        gemm_mf<4><<<dim3(B_ / 64, G4 / 64), 256, 0, stream>>>(
            ctxb, Wih2_b, H_, H_, 0, gates, hb, nullptr,
            nullptr, nullptr, cbuf, hid, nullptr, t == T_ - 1);
    }
    // logits + lsm for final step
    gemm_mf<0><<<dim3(B_ / 64, V_ / 64), 256, 0, stream>>>(
        hb, Wcat_b + (size_t)5120 * H_, H_, H_, V_, lgbuf, nullptr, out_b,
        nullptr, nullptr, nullptr, nullptr, nullptr, 0);
    lsm_kernel<<<B_, 256, 0, stream>>>(lgbuf, lp, T_ - 1);
}

// Round 5
// 6871.503 us; speedup vs baseline: 8.4740x; 1.1575x over previous
//
#include <hip/hip_runtime.h>

#define B_ 128
#define S_ 256
#define H_ 1024
#define V_ 512
#define T_ 128
#define G4 4096

typedef __attribute__((ext_vector_type(8))) short bf16x8;
typedef __attribute__((ext_vector_type(4))) float f32x4;

// ---------- helpers ----------
__device__ __forceinline__ float bf2f(unsigned short x) {
    unsigned int u = ((unsigned int)x) << 16;
    return __builtin_bit_cast(float, u);
}
__device__ __forceinline__ unsigned short f2b(float f) {
    unsigned int u = __builtin_bit_cast(unsigned int, f);
    u = u + 0x7fffu + ((u >> 16) & 1u);
    return (unsigned short)(u >> 16);
}
__device__ __forceinline__ float ftanh(float x) {
    float e = __expf(2.f * x);
    return 1.f - 2.f * __builtin_amdgcn_rcpf(e + 1.f);
}
__device__ __forceinline__ float fsigm(float x) {
    return __builtin_amdgcn_rcpf(1.f + __expf(-x));
}
__device__ __forceinline__ void gll16(const void* g, void* l) {
    __builtin_amdgcn_global_load_lds(
        (const __attribute__((address_space(1))) unsigned int*)g,
        (__attribute__((address_space(3))) unsigned int*)l, 16, 0, 0);
}

// ---------- small precompute kernels ----------
__global__ void f32_to_bf16_x4(const float4* __restrict__ in, ushort4* __restrict__ out, int n4) {
    int i = blockIdx.x * 256 + threadIdx.x;
    if (i < n4) {
        float4 v = in[i];
        ushort4 o;
        o.x = f2b(v.x); o.y = f2b(v.y); o.z = f2b(v.z); o.w = f2b(v.w);
        out[i] = o;
    }
}

// dst[r][0..1023] (bf16) = src[perm(r)][coff..coff+1023]; perm: gate-interleave or identity
__global__ void cvt_gather(const float* __restrict__ src, int src_ld, int coff,
                           unsigned short* __restrict__ dst, int perm) {
    int i = blockIdx.x * 256 + threadIdx.x;
    int r = i >> 8;
    int c = (i & 255) * 4;
    int sr = perm ? (((r & 3) << 10) + (r >> 2)) : r;
    float4 v = *reinterpret_cast<const float4*>(src + (size_t)sr * src_ld + coff + c);
    ushort4 o;
    o.x = f2b(v.x); o.y = f2b(v.y); o.z = f2b(v.z); o.w = f2b(v.w);
    *reinterpret_cast<ushort4*>(dst + (size_t)r * 1024 + c) = o;
}

__global__ void build_toks(const int* __restrict__ target, int* __restrict__ toks) {
    int idx = blockIdx.x * 256 + threadIdx.x;
    if (idx < T_ * B_) {
        int t = idx / B_, b = idx % B_;
        toks[idx] = (t == 0) ? 0 : target[b * T_ + t - 1];
    }
}

__global__ void build_bsum(const float* __restrict__ b_ih, const float* __restrict__ b_hh,
                           float* __restrict__ bsum) {
    int j = blockIdx.x * 256 + threadIdx.x;
    if (j < G4) {
        int pj = ((j & 3) << 10) + (j >> 2);
        bsum[j] = b_ih[pj] + b_hh[pj];
    }
}

// ---------- bf16 MFMA GEMM, BK=128, depth-2 pipeline with COUNTED vmcnt ----------
// C[M,N] = A[M,K](bf16) * Bw[N,ldb](bf16)^T, 64x64 tile, 4 waves. K must be >=256, mult of 128.
// Loop: vmcnt(8)->barrier (tile k landed; prev reads done) -> ds_read -> lgkmcnt(0)
//       -> barrier (all reads of buf done) -> stage(k+2) -> MFMA. Loads for tile k+1
//       stay in flight across barriers (T4); only last iter drains vmcnt(0).
template<int MODE>
__global__ __launch_bounds__(256) void gemm_mf(
    const unsigned short* __restrict__ A,
    const unsigned short* __restrict__ Bw,
    int K, int ldb, int ldc,
    float* __restrict__ C, unsigned short* __restrict__ Cb,
    const float* __restrict__ bias,
    const float* __restrict__ Pemb,
    const int* __restrict__ toks,
    float* __restrict__ Cq,
    float* __restrict__ Lg,
    const float* __restrict__ bias2,
    int flag)
{
    __shared__ unsigned short As[2 * 8192];   // 64 rows x 128 cols, double-buffered
    __shared__ unsigned short Bs[2 * 8192];
    const int tid = threadIdx.x;
    const int lane = tid & 63;
    const int wv = tid >> 6;
    const int m0 = blockIdx.x * 64;
    const int n0 = blockIdx.y * 64;

    // staging: 1024 16B-chunks per matrix, 4 per thread; slot XOR-swizzled by row
    const unsigned short* ga[4];
    const unsigned short* gb[4];
    #pragma unroll
    for (int j = 0; j < 4; ++j) {
        int ci = tid + 256 * j;
        int row = ci >> 4;
        int src = (ci & 15) ^ (row & 7);
        ga[j] = A + (size_t)(m0 + row) * K + src * 8;
        gb[j] = Bw + (size_t)(n0 + row) * ldb + src * 8;
    }

    f32x4 acc[2][2] = {};
    const int r0 = (wv >> 1) * 32;
    const int cq0 = (wv & 1) * 32;
    const int fr = lane & 15;
    const int kg = lane >> 4;

    auto stage = [&](int k0, int p) {
        #pragma unroll
        for (int j = 0; j < 4; ++j) {
            gll16(ga[j] + k0, As + p * 8192 + j * 2048 + wv * 512);
            gll16(gb[j] + k0, Bs + p * 8192 + j * 2048 + wv * 512);
        }
    };

    stage(0, 0);
    stage(128, 1);
    int p = 0;
    for (int k0 = 0; k0 < K; k0 += 128) {
        if (k0 + 128 < K) {
            asm volatile("s_waitcnt vmcnt(8)" ::: "memory");   // tile k landed (mine)
        } else {
            asm volatile("s_waitcnt vmcnt(0)" ::: "memory");   // last tile: drain
        }
        __builtin_amdgcn_sched_barrier(0);
        __builtin_amdgcn_s_barrier();                           // everyone's tile k landed
        __builtin_amdgcn_sched_barrier(0);
        const unsigned short* Ab = As + p * 8192;
        const unsigned short* Bb = Bs + p * 8192;
        bf16x8 af[2][4], bfr[2][4];
        #pragma unroll
        for (int f = 0; f < 2; ++f)
            #pragma unroll
            for (int kh = 0; kh < 4; ++kh) {
                int ra = r0 + f * 16 + fr;
                af[f][kh] = *(const bf16x8*)&Ab[ra * 128 + (((kh * 4 + kg) ^ (ra & 7)) << 3)];
                int rb = cq0 + f * 16 + fr;
                bfr[f][kh] = *(const bf16x8*)&Bb[rb * 128 + (((kh * 4 + kg) ^ (rb & 7)) << 3)];
            }
        asm volatile("s_waitcnt lgkmcnt(0)" ::: "memory");      // my ds_reads done
        __builtin_amdgcn_sched_barrier(0);
        __builtin_amdgcn_s_barrier();                           // all reads of buf p done
        __builtin_amdgcn_sched_barrier(0);
        if (k0 + 256 < K) stage(k0 + 256, p);                   // overwrite buf p
        #pragma unroll
        for (int f = 0; f < 2; ++f)
            #pragma unroll
            for (int g = 0; g < 2; ++g)
                #pragma unroll
                for (int kh = 0; kh < 4; ++kh)
                    acc[f][g] = __builtin_amdgcn_mfma_f32_16x16x32_bf16(
                        af[f][kh], bfr[g][kh], acc[f][g], 0, 0, 0);
        p ^= 1;
    }

    const int erow = (lane >> 4) * 4;
    const int ecol = lane & 15;

    if constexpr (MODE == 4) {
        __shared__ float Lt[64 * 64];
        __syncthreads();
        #pragma unroll
        for (int f = 0; f < 2; ++f)
            #pragma unroll
            for (int g = 0; g < 2; ++g)
                #pragma unroll
                for (int r = 0; r < 4; ++r)
                    Lt[(r0 + f * 16 + erow + r) * 64 + cq0 + g * 16 + ecol] = acc[f][g][r];
        __syncthreads();
        #pragma unroll
        for (int i = 0; i < 4; ++i) {
            int pi = tid + 256 * i;
            int r = pi >> 4, u = pi & 15;
            int b = m0 + r;
            int hh = (n0 >> 2) + u;
            f32x4 gv = *reinterpret_cast<const f32x4*>(&Lt[r * 64 + u * 4]);
            const float* gp = C + (size_t)b * G4 + n0 + u * 4;
            float iv = gv[0] + gp[0];
            float fv = gv[1] + gp[1];
            float gg = gv[2] + gp[2];
            float ov = gv[3] + gp[3];
            int ci = b * H_ + hh;
            float cn = fsigm(fv) * Cq[ci] + fsigm(iv) * ftanh(gg);
            float hn = fsigm(ov) * ftanh(cn);
            Cq[ci] = cn;
            Cb[ci] = f2b(hn);
            if (flag) Lg[ci] = hn;
        }
    } else {
        #pragma unroll
        for (int f = 0; f < 2; ++f) {
            #pragma unroll
            for (int g = 0; g < 2; ++g) {
                #pragma unroll
                for (int r = 0; r < 4; ++r) {
                    int row = m0 + r0 + f * 16 + erow + r;
                    int col = n0 + cq0 + g * 16 + ecol;
                    float v = acc[f][g][r];
                    if (MODE == 0) {
                        C[(size_t)row * ldc + col] = v + bias[col];
                    } else if (MODE == 1) {
                        Cb[(size_t)row * ldc + col] = f2b(v + bias[col]);
                    } else if (MODE == 2) {
                        if (col < H_) {
                            Cq[(size_t)row * H_ + col] = v + bias[col];
                        } else if (col < 5120) {
                            int cg = col - H_;
                            C[(size_t)row * G4 + cg] = v + Pemb[(size_t)toks[row] * G4 + cg];
                        } else {
                            int cl = col - 5120;
                            Lg[(size_t)row * V_ + cl] = v + bias2[cl];
                        }
                    }
                }
            }
        }
    }
}

// ---------- attention energies + partial context (+ lsm of t-1), grid (B,16) x 256 ----------
__global__ __launch_bounds__(256) void attn_e(
    const unsigned short* __restrict__ kp,   // [B*S, H] bf16
    const float* __restrict__ q,             // [B, H]
    const float* __restrict__ Va,            // [H]
    const unsigned short* __restrict__ encb, // [B*S, H] bf16
    float* __restrict__ es_g,                // [B, S]
    float* __restrict__ pctx,                // [B, 16, H] unnormalized partial ctx
    const float* __restrict__ lg,            // [B, V] logits t-1
    float* __restrict__ lp,                  // [B,T,V]
    int t)
{
    const int b = blockIdx.x;
    const int sh = blockIdx.y;  // s-chunk of 16
    const int tid = threadIdx.x;
    const int lane = tid & 63;
    const int wv = tid >> 6;    // 0..3
    __shared__ float qs[H_];
    __shared__ float vas[H_];
    __shared__ float es[16], pe[16];
    __shared__ float redm[4], reds[4];

    *reinterpret_cast<float4*>(&qs[tid * 4]) =
        *reinterpret_cast<const float4*>(&q[(size_t)b * H_ + tid * 4]);
    *reinterpret_cast<float4*>(&vas[tid * 4]) =
        *reinterpret_cast<const float4*>(&Va[tid * 4]);

    // ---- log-softmax(t-1), sh==0 blocks only; barriers unconditional ----
    const bool doL = (t > 0) && (sh == 0);
    float a0 = doL ? lg[(size_t)b * V_ + tid] : -3.4e38f;
    float a1 = doL ? lg[(size_t)b * V_ + 256 + tid] : -3.4e38f;
    float mx = fmaxf(a0, a1);
    #pragma unroll
    for (int off = 32; off; off >>= 1) mx = fmaxf(mx, __shfl_xor(mx, off));
    if (lane == 0) redm[wv] = mx;
    __syncthreads();                         // also publishes qs/vas
    mx = fmaxf(fmaxf(redm[0], redm[1]), fmaxf(redm[2], redm[3]));
    float sm = doL ? (__expf(a0 - mx) + __expf(a1 - mx)) : 0.f;
    #pragma unroll
    for (int off = 32; off; off >>= 1) sm += __shfl_xor(sm, off);
    if (lane == 0) reds[wv] = sm;
    __syncthreads();
    if (doL) {
        sm = reds[0] + reds[1] + reds[2] + reds[3];
        float lse = mx + __logf(sm);
        size_t off = ((size_t)b * T_ + (t - 1)) * V_;
        lp[off + tid] = a0 - lse;
        lp[off + tid + 256] = a1 - lse;
    }

    // ---- energies: wave wv handles s_loc = wv*4 + 0..3 ----
    #pragma unroll
    for (int si = 0; si < 4; ++si) {
        int s_loc = wv * 4 + si;
        const unsigned short* kr = kp + (size_t)(b * S_ + sh * 16 + s_loc) * H_;
        float acc = 0.f;
        #pragma unroll
        for (int it = 0; it < 4; ++it) {
            int h4 = lane * 4 + it * 256;
            ushort4 u = *reinterpret_cast<const ushort4*>(kr + h4);
            acc += vas[h4 + 0] * ftanh(qs[h4 + 0] + bf2f(u.x));
            acc += vas[h4 + 1] * ftanh(qs[h4 + 1] + bf2f(u.y));
            acc += vas[h4 + 2] * ftanh(qs[h4 + 2] + bf2f(u.z));
            acc += vas[h4 + 3] * ftanh(qs[h4 + 3] + bf2f(u.w));
        }
        #pragma unroll
        for (int off = 32; off; off >>= 1) acc += __shfl_down(acc, off);
        if (lane == 0) {
            es[s_loc] = acc;
            es_g[(size_t)b * S_ + sh * 16 + s_loc] = acc;
        }
    }
    __syncthreads();

    // ---- partial context with local-max scaling ----
    float mb = es[0];
    #pragma unroll
    for (int i = 1; i < 16; ++i) mb = fmaxf(mb, es[i]);
    if (tid < 16) pe[tid] = __expf(es[tid] - mb);
    __syncthreads();
    const int c0 = tid * 4;
    float ax = 0.f, ay = 0.f, az = 0.f, aw = 0.f;
    #pragma unroll
    for (int sl = 0; sl < 16; ++sl) {
        ushort4 u = *reinterpret_cast<const ushort4*>(
            &encb[(size_t)(b * S_ + sh * 16 + sl) * H_ + c0]);
        float w = pe[sl];
        ax += w * bf2f(u.x);
        ay += w * bf2f(u.y);
        az += w * bf2f(u.z);
        aw += w * bf2f(u.w);
    }
    float4 o4; o4.x = ax; o4.y = ay; o4.z = az; o4.w = aw;
    *reinterpret_cast<float4*>(&pctx[((size_t)b * 16 + sh) * H_ + c0]) = o4;
}

// ---------- combine: exact softmax + attn-weight store + ctx finalize, grid B x 256 ----------
__global__ __launch_bounds__(256) void attn_comb(
    const float* __restrict__ es_g,          // [B, S]
    const float* __restrict__ pctx,          // [B, 16, H]
    unsigned short* __restrict__ ctxb,       // [B, H] bf16
    float* __restrict__ attnOut,             // [B,T,S]
    int t)
{
    const int b = blockIdx.x;
    const int tid = threadIdx.x;
    const int lane = tid & 63;
    const int wv = tid >> 6;
    __shared__ float es[S_], sc[16];
    __shared__ float redm[4], reds[4];

    float x = es_g[(size_t)b * S_ + tid];
    es[tid] = x;
    float mx = x;
    #pragma unroll
    for (int off = 32; off; off >>= 1) mx = fmaxf(mx, __shfl_xor(mx, off));
    if (lane == 0) redm[wv] = mx;
    __syncthreads();                          // publishes es too
    mx = fmaxf(fmaxf(redm[0], redm[1]), fmaxf(redm[2], redm[3]));
    float ex = __expf(x - mx);
    float sm = ex;
    #pragma unroll
    for (int off = 32; off; off >>= 1) sm += __shfl_xor(sm, off);
    if (lane == 0) reds[wv] = sm;
    __syncthreads();
    sm = reds[0] + reds[1] + reds[2] + reds[3];
    float rZ = __builtin_amdgcn_rcpf(sm);
    attnOut[((size_t)(b * T_ + t)) * S_ + tid] = ex * rZ;
    if (tid < 16) {
        float mb = es[tid * 16];
        #pragma unroll
        for (int j = 1; j < 16; ++j) mb = fmaxf(mb, es[tid * 16 + j]);
        sc[tid] = __expf(mb - mx);
    }
    __syncthreads();
    const int c0 = tid * 4;
    float ax = 0.f, ay = 0.f, az = 0.f, aw = 0.f;
    #pragma unroll
    for (int blk = 0; blk < 16; ++blk) {
        float4 pv = *reinterpret_cast<const float4*>(
            &pctx[((size_t)b * 16 + blk) * H_ + c0]);
        float s = sc[blk];
        ax += s * pv.x; ay += s * pv.y; az += s * pv.z; aw += s * pv.w;
    }
    ushort4 o;
    o.x = f2b(ax * rZ); o.y = f2b(ay * rZ); o.z = f2b(az * rZ); o.w = f2b(aw * rZ);
    *reinterpret_cast<ushort4*>(&ctxb[(size_t)b * H_ + c0]) = o;
}

// ---------- standalone log-softmax (final step only) ----------
__global__ __launch_bounds__(256) void lsm_kernel(
    const float* __restrict__ lg, float* __restrict__ lp, int t)
{
    int b = blockIdx.x, tid = threadIdx.x;
    int lane = tid & 63, wv = tid >> 6;
    __shared__ float red[4];
    float a0 = lg[(size_t)b * V_ + tid];
    float a1 = lg[(size_t)b * V_ + 256 + tid];
    float mx = fmaxf(a0, a1);
    #pragma unroll
    for (int off = 32; off; off >>= 1) mx = fmaxf(mx, __shfl_xor(mx, off));
    if (lane == 0) red[wv] = mx;
    __syncthreads();
    mx = fmaxf(fmaxf(red[0], red[1]), fmaxf(red[2], red[3]));
    float sm = __expf(a0 - mx) + __expf(a1 - mx);
    #pragma unroll
    for (int off = 32; off; off >>= 1) sm += __shfl_xor(sm, off);
    __syncthreads();
    if (lane == 0) red[wv] = sm;
    __syncthreads();
    sm = red[0] + red[1] + red[2] + red[3];
    float lse = mx + __logf(sm);
    size_t off = ((size_t)b * T_ + t) * V_;
    lp[off + tid] = a0 - lse;
    lp[off + tid + 256] = a1 - lse;
}

// ---------- launch ----------
extern "C" void kernel_launch(void* const* d_in, const int* in_sizes, int n_in,
                              void* d_out, int out_size, void* d_ws, size_t ws_size,
                              hipStream_t stream) {
    const float* enc   = (const float*)d_in[0];
    const float* h0    = (const float*)d_in[1];
    const float* c0    = (const float*)d_in[2];
    const int*   targ  = (const int*)d_in[3];
    const float* emb   = (const float*)d_in[5];
    const float* Wa_w  = (const float*)d_in[6];
    const float* Wa_b  = (const float*)d_in[7];
    const float* Ua_w  = (const float*)d_in[8];
    const float* Ua_b  = (const float*)d_in[9];
    const float* Va_w  = (const float*)d_in[10];
    const float* W_ih  = (const float*)d_in[12];
    const float* W_hh  = (const float*)d_in[13];
    const float* b_ih  = (const float*)d_in[14];
    const float* b_hh  = (const float*)d_in[15];
    const float* out_w = (const float*)d_in[16];
    const float* out_b = (const float*)d_in[17];

    float* out  = (float*)d_out;
    float* lp   = out;                          // [B,T,V]
    float* hid  = out + (size_t)B_ * T_ * V_;   // [1,B,H]
    float* attn = hid + (size_t)B_ * H_;        // [B,T,S]

    char* w = (char*)d_ws;
    auto alloc = [&](size_t bytes) {
        char* p = w;
        w += (bytes + 255) & ~(size_t)255;
        return p;
    };
    const size_t NKP = (size_t)B_ * S_ * H_;
    unsigned short* kp     = (unsigned short*)alloc(NKP * 2);
    unsigned short* encb   = (unsigned short*)alloc(NKP * 2);
    unsigned short* Wcat_b = (unsigned short*)alloc((size_t)5632 * H_ * 2); // [Wa; W_hh(perm); out_w]
    unsigned short* Wih1_b = (unsigned short*)alloc((size_t)G4 * H_ * 2);   // W_ih[:, :H] perm
    unsigned short* Wih2_b = (unsigned short*)alloc((size_t)G4 * H_ * 2);   // W_ih[:, H:] perm
    unsigned short* Uaw_b  = (unsigned short*)alloc((size_t)H_ * H_ * 2);
    unsigned short* emb_b  = (unsigned short*)alloc((size_t)V_ * H_ * 2);
    unsigned short* hb     = (unsigned short*)alloc((size_t)B_ * H_ * 2);
    unsigned short* ctxb   = (unsigned short*)alloc((size_t)B_ * H_ * 2);
    float* Pemb  = (float*)alloc((size_t)V_ * G4 * 4);
    float* bsumP = (float*)alloc((size_t)G4 * 4);
    int*   toks  = (int*)alloc((size_t)T_ * B_ * 4);
    float* cbuf  = (float*)alloc((size_t)B_ * H_ * 4);
    float* qbuf  = (float*)alloc((size_t)B_ * H_ * 4);
    float* gates = (float*)alloc((size_t)B_ * G4 * 4);
    float* lgbuf = (float*)alloc((size_t)B_ * V_ * 4);
    float* es_g  = (float*)alloc((size_t)B_ * S_ * 4);
    float* pctx  = (float*)alloc((size_t)B_ * 16 * H_ * 4);
    if ((size_t)(w - (char*)d_ws) > ws_size) return;

    auto cvt = [&](const float* src, unsigned short* dst, size_t n) {
        int n4 = (int)(n / 4);
        f32_to_bf16_x4<<<(n4 + 255) / 256, 256, 0, stream>>>((const float4*)src, (ushort4*)dst, n4);
    };

    // precompute
    cvt(enc, encb, NKP);
    cvt(Ua_w, Uaw_b, (size_t)H_ * H_);
    cvt(emb, emb_b, (size_t)V_ * H_);
    cvt(h0, hb, (size_t)B_ * H_);
    cvt_gather<<<1024, 256, 0, stream>>>(Wa_w, H_, 0, Wcat_b, 0);
    cvt_gather<<<4096, 256, 0, stream>>>(W_hh, H_, 0, Wcat_b + (size_t)1024 * H_, 1);
    cvt_gather<<<512, 256, 0, stream>>>(out_w, H_, 0, Wcat_b + (size_t)5120 * H_, 0);
    cvt_gather<<<4096, 256, 0, stream>>>(W_ih, 2 * H_, 0, Wih1_b, 1);
    cvt_gather<<<4096, 256, 0, stream>>>(W_ih, 2 * H_, H_, Wih2_b, 1);
    build_toks<<<(T_ * B_ + 255) / 256, 256, 0, stream>>>(targ, toks);
    build_bsum<<<(G4 + 255) / 256, 256, 0, stream>>>(b_ih, b_hh, bsumP);
    hipMemcpyAsync(cbuf, c0, (size_t)B_ * H_ * 4, hipMemcpyDeviceToDevice, stream);

    // keys_proj: kp = encb @ Ua_w^T + Ua_b (bf16 out)
    gemm_mf<1><<<dim3((B_ * S_) / 64, H_ / 64), 256, 0, stream>>>(
        encb, Uaw_b, H_, H_, H_, nullptr, kp, Ua_b,
        nullptr, nullptr, nullptr, nullptr, nullptr, 0);
    // Pemb (permuted): emb @ W_ih[:, :H](perm)^T + bsumP
    gemm_mf<0><<<dim3(V_ / 64, G4 / 64), 256, 0, stream>>>(
        emb_b, Wih1_b, H_, H_, G4, Pemb, nullptr, bsumP,
        nullptr, nullptr, nullptr, nullptr, nullptr, 0);

    // sequential decode: 4 launches per step
    for (int t = 0; t < T_; ++t) {
        gemm_mf<2><<<dim3(B_ / 64, 5632 / 64), 256, 0, stream>>>(
            hb, Wcat_b, H_, H_, 0, gates, nullptr, Wa_b,
            Pemb, toks + t * B_, qbuf, lgbuf, out_b, 0);
        attn_e<<<dim3(B_, 16), 256, 0, stream>>>(kp, qbuf, Va_w, encb, es_g, pctx, lgbuf, lp, t);
        attn_comb<<<B_, 256, 0, stream>>>(es_g, pctx, ctxb, attn, t);
        gemm_mf<4><<<dim3(B_ / 64, G4 / 64), 256, 0, stream>>>(
            ctxb, Wih2_b, H_, H_, 0, gates, hb, nullptr,
            nullptr, nullptr, cbuf, hid, nullptr, t == T_ - 1);
    }
    // logits + lsm for final step
    gemm_mf<0><<<dim3(B_ / 64, V_ / 64), 256, 0, stream>>>(
        hb, Wcat_b + (size_t)5120 * H_, H_, H_, V_, lgbuf, nullptr, out_b,
        nullptr, nullptr, nullptr, nullptr, nullptr, 0);
    lsm_kernel<<<B_, 256, 0, stream>>>(lgbuf, lp, T_ - 1);
}